// Round 19
// baseline (1249.409 us; speedup 1.0000x reference)
//
#include <hip/hip_runtime.h>
#include <math.h>

// FNO3d forward. B=8,T=10,H=128,W=128, C=64, NL=4, modes kt8 kh16 kw8.
// x stored FP16, layout xT[(b*10+t)*128+h][w][ci].
// Round 19: r18 + invW launch_bounds (256,4)->(256,7). With 48 VGPR / 20.5KB
// LDS the (256,4) declaration itself was the occupancy cap (51% == 16 waves).
// (256,7) targets the LDS limit (7 blocks/CU, 28 waves); VGPR cap 73 > 48.

#define TWO_PI 6.2831853071795864769f
#define ORTHO_SC 2.4705294220065465e-3f  // 1/sqrt(10*128*128)

typedef unsigned short u16;
typedef _Float16 f16;
typedef __attribute__((ext_vector_type(8))) _Float16 f16x8;
typedef __attribute__((ext_vector_type(4))) float f32x4;

#define MFMAH(acc, a, b) acc = __builtin_amdgcn_mfma_f32_16x16x32_f16(a, b, acc, 0, 0, 0)

__device__ __forceinline__ u16 f16b(float v) {
  f16 h = (f16)v;
  return __builtin_bit_cast(u16, h);
}
__device__ __forceinline__ float f16lo(float v) {  // v - fp16(v)
  f16 h = (f16)v;
  return v - (float)h;
}
__device__ __forceinline__ float f16f(u16 b) {
  return (float)__builtin_bit_cast(f16, b);
}
// tanh-approx GELU via exp2 (~9 VALU ops)
__device__ __forceinline__ float gelu_fast(float x) {
  float u = 0.7978845608f * (x + 0.044715f * x * x * x);
  float a = fminf(u * 2.885390082f, 30.0f);
  float e = __builtin_exp2f(a);
  return x * e * __builtin_amdgcn_rcpf(e + 1.0f);
}

// ---------------- prep: A-fragments (split fp16) + twiddle tables ----------------
// swf: [layer4][strip4][kb2][hl2][lane64][8]
// awf: [strip4][t10][kc2][hl2][lane64][8]
// Tt : [hl2][w128][kk32]
// twf: [w128][k8] float2
// Ef : [hl2][kc4][lane64][8]
// f1f: [strip8][kc3][hl2][lane64][8]  (head fc1^T; k=66 row = fc1_b)
__global__ __launch_bounds__(256) void k_prep2(const float* __restrict__ skip_w,
                                               const float* __restrict__ agg_w,
                                               const float* __restrict__ fc1_w,
                                               const float* __restrict__ fc1_b,
                                               u16* __restrict__ swf,
                                               u16* __restrict__ awf,
                                               u16* __restrict__ Tt,
                                               float2* __restrict__ twf,
                                               u16* __restrict__ Ef,
                                               u16* __restrict__ f1f) {
  int e = blockIdx.x*256 + threadIdx.x;
  if (e < 32768) {
    int j = e & 7, lane = (e >> 3) & 63, half = (e >> 9) & 1, ks = (e >> 10) & 1;
    int strip = (e >> 11) & 3, layer = e >> 13;
    int co = strip*16 + (lane & 15);
    int ci = ks*32 + (lane >> 4)*8 + j;
    float v = skip_w[((size_t)(layer*64) + co)*64 + ci];
    swf[e] = half ? f16b(f16lo(v)) : f16b(v);
  } else if (e < 114688) {
    int ee = e - 32768;
    int j = ee & 7, lane = (ee >> 3) & 63;
    int v9 = ee >> 9;
    int half = v9 & 1; v9 >>= 1;
    int ks = v9 & 1; v9 >>= 1;
    int t = v9 % 10, strip = v9 / 10;
    int co = strip*16 + (lane & 15);
    int ci = ks*32 + (lane >> 4)*8 + j;
    float v = agg_w[((size_t)co*64 + ci)*10 + t];
    awf[ee] = half ? f16b(f16lo(v)) : f16b(v);
  } else if (e < 122880) {
    int ee = e - 114688;
    int half = ee >> 12, r = ee & 4095, w = r >> 5, kk = r & 31;
    int m = kk >> 1;
    float val;
    if (kk >= 16) val = 0.f;
    else if (kk == 0) val = 1.f;
    else if (kk == 1) val = 0.f;
    else {
      float th = TWO_PI * (float)m * (float)w / 128.0f;
      val = (kk & 1) ? (-2.f*sinf(th)) : (2.f*cosf(th));
    }
    Tt[ee] = half ? f16b(f16lo(val)) : f16b(val);
  } else if (e < 123904) {
    int ee = e - 122880;
    int w = ee >> 3, k = ee & 7;
    float th = TWO_PI * (float)k * (float)w / 128.0f;
    twf[ee] = make_float2(cosf(th), -sinf(th));
  } else if (e < 125952) {
    int ee = e - 123904;
    int j = ee & 7, lane = (ee >> 3) & 63, kc = ee >> 9;
    int n = lane & 15, g = lane >> 4;
    int w = kc*32 + g*8 + j;
    int k = n >> 1;
    float th = TWO_PI * (float)k * (float)w / 128.0f;
    float val = (n & 1) ? (-sinf(th)) : cosf(th);
    Ef[ee] = f16b(val);
    Ef[2048 + ee] = f16b(f16lo(val));
  } else if (e < 150528) {
    int ee = e - 125952;
    int j = ee & 7, lane = (ee >> 3) & 63, hl = (ee >> 9) & 1;
    int rest = ee >> 10;         // 0..23
    int kc = rest % 3, strip = rest / 3;
    int o = strip*16 + (lane & 15);
    int k = kc*32 + (lane >> 4)*8 + j;
    float v;
    if (k < 66) v = fc1_w[(size_t)k*128 + o];
    else if (k == 66) v = fc1_b[o];
    else v = 0.f;
    f1f[ee] = hl ? f16b(f16lo(v)) : f16b(v);
  }
}

// ---------------- fused lift + layer-0 forward-W DFT (fp16 xw) ----------------
__global__ __launch_bounds__(128) void k_lift_fwdW(const float* __restrict__ frames,
                                                   const float* __restrict__ times,
                                                   const float* __restrict__ lift_w,
                                                   const float* __restrict__ lift_b,
                                                   const float2* __restrict__ twf,
                                                   u16* __restrict__ xT,
                                                   u16* __restrict__ xw16) {
  __shared__ u16 xs[64][130];
  __shared__ float2 tws[128][8];
  __shared__ float fr[128];
  __shared__ float lw0[64], lw1a[64];
  int bth = blockIdx.x;
  int h = bth & 127; int bt = bth >> 7; int t = bt % 10, b = bt / 10;
  int tid = threadIdx.x;
  for (int i = tid; i < 1024; i += 128) tws[i >> 3][i & 7] = twf[i];
  float tv = times[b*10 + t];
  fr[tid] = frames[((size_t)(b*10 + t)*128 + h)*128 + tid];
  if (tid < 64) { lw0[tid] = lift_w[2*tid]; lw1a[tid] = lift_w[2*tid+1]*tv + lift_b[tid]; }
  __syncthreads();
  {
    int w = tid;
    float f = fr[w];
    unsigned pk[32];
    #pragma unroll
    for (int q = 0; q < 32; ++q) {
      float v0 = f*lw0[2*q] + lw1a[2*q];
      float v1 = f*lw0[2*q+1] + lw1a[2*q+1];
      u16 h0 = f16b(v0), h1 = f16b(v1);
      xs[2*q][w] = h0; xs[2*q+1][w] = h1;
      pk[q] = (unsigned)h0 | ((unsigned)h1 << 16);
    }
    uint4* d4 = (uint4*)(xT + (size_t)bth*8192 + w*64);
    #pragma unroll
    for (int q = 0; q < 8; ++q)
      d4[q] = make_uint4(pk[4*q], pk[4*q+1], pk[4*q+2], pk[4*q+3]);
  }
  __syncthreads();
  {
    int lane = tid & 63, wv = tid >> 6;
    float ar[4] = {0,0,0,0}, ai[4] = {0,0,0,0};
    for (int w2 = 0; w2 < 128; ++w2) {
      float xu = f16f(xs[lane][w2]);
      #pragma unroll
      for (int kk = 0; kk < 4; ++kk) {
        float2 ew = tws[w2][wv*4 + kk];
        ar[kk] += xu*ew.x; ai[kk] += xu*ew.y;
      }
    }
    size_t row = ((size_t)(b*64 + lane)*10 + t)*128 + h;
    unsigned p0 = (unsigned)f16b(ar[0]) | ((unsigned)f16b(ai[0]) << 16);
    unsigned p1 = (unsigned)f16b(ar[1]) | ((unsigned)f16b(ai[1]) << 16);
    unsigned p2 = (unsigned)f16b(ar[2]) | ((unsigned)f16b(ai[2]) << 16);
    unsigned p3 = (unsigned)f16b(ar[3]) | ((unsigned)f16b(ai[3]) << 16);
    *(uint4*)(xw16 + row*16 + wv*8) = make_uint4(p0, p1, p2, p3);
  }
}

// ---------------- fused forward H+T stages (fp16 xw input) ----------------
__global__ __launch_bounds__(256) void k_fwdHT(const unsigned* __restrict__ xw32,
                                               float2* __restrict__ xf) {
  __shared__ unsigned tile[2][1024];
  __shared__ float2 parts1[1024];
  __shared__ float2 tw128[128];
  int bc = blockIdx.x;
  int b = bc >> 6, c = bc & 63;
  int tid = threadIdx.x;
  if (tid < 128) {
    float s, co; sincosf(TWO_PI * (float)tid / 128.0f, &s, &co);
    tw128[tid] = make_float2(co, -s);
  }
  int tpar = tid >> 7, j = tid & 127;
  int khi = j >> 3, kwi = j & 7;
  int kh = (khi < 8) ? khi : (112 + khi);
  float accr[8], acci[8];
  #pragma unroll
  for (int k = 0; k < 8; ++k) { accr[k] = 0.f; acci[k] = 0.f; }
  for (int tt = 0; tt < 5; ++tt) {
    __syncthreads();
    for (int u = tid; u < 2048; u += 256) {
      int tg = u >> 10, idx = u & 1023;
      tile[tg][idx] = xw32[((size_t)bc*10 + tg*5 + tt)*1024 + idx];
    }
    __syncthreads();
    float xr = 0.f, xi = 0.f;
    for (int h = 0; h < 128; ++h) {
      unsigned uv = tile[tpar][h*8 + kwi];
      float vx = f16f((u16)uv);
      float vy = f16f((u16)(uv >> 16));
      float2 tw = tw128[(h*kh) & 127];
      xr += vx*tw.x - vy*tw.y;
      xi += vx*tw.y + vy*tw.x;
    }
    int t = tpar*5 + tt;
    float sb, cb; sincosf(TWO_PI * (float)t / 10.0f, &sb, &cb);
    float p_r[10], p_i[10];
    p_r[0] = 1.f; p_i[0] = 0.f; p_r[1] = cb; p_i[1] = -sb;
    #pragma unroll
    for (int k = 2; k < 10; ++k) {
      p_r[k] = p_r[k-1]*p_r[1] - p_i[k-1]*p_i[1];
      p_i[k] = p_r[k-1]*p_i[1] + p_i[k-1]*p_r[1];
    }
    #pragma unroll
    for (int kti = 0; kti < 8; ++kti) {
      int kt = (kti < 4) ? kti : kti + 2;
      accr[kti] += xr*p_r[kt] - xi*p_i[kt];
      acci[kti] += xr*p_i[kt] + xi*p_r[kt];
    }
  }
  __syncthreads();
  if (tpar == 1) {
    #pragma unroll
    for (int kti = 0; kti < 8; ++kti)
      parts1[j*8 + kti] = make_float2(accr[kti], acci[kti]);
  }
  __syncthreads();
  if (tpar == 0) {
    #pragma unroll
    for (int kti = 0; kti < 8; ++kti) {
      float2 bq = parts1[j*8 + kti];
      xf[((size_t)b*1024 + kti*128 + j)*64 + c] =
          make_float2((accr[kti] + bq.x)*ORTHO_SC, (acci[kti] + bq.y)*ORTHO_SC);
    }
  }
}

// ---------------- channel mix (reads spec_w original layout directly) ----------------
__global__ __launch_bounds__(256) void k_mix(const float2* __restrict__ xf,
                                             const float* __restrict__ spec_w_l,
                                             float2* __restrict__ yf) {
  __shared__ float2 xfs[8][4][64];
  int m0 = blockIdx.x * 4;
  for (int i = threadIdx.x; i < 2048; i += 256) {
    int bb = i >> 8, mi = (i >> 6) & 3, ci = i & 63;
    xfs[bb][mi][ci] = xf[((size_t)bb*1024 + m0 + mi)*64 + ci];
  }
  __syncthreads();
  int co = threadIdx.x & 63, mi = threadIdx.x >> 6;
  int m = m0 + mi;
  int kti = m >> 7, khi = (m >> 3) & 15, kwi = m & 7;
  int q = ((kti >= 4) ? 2 : 0) + ((khi >= 8) ? 1 : 0);
  int modeidx = ((kti & 3)*8 + (khi & 7))*8 + kwi;
  const float2* wp = (const float2*)spec_w_l
                     + ((size_t)(q*64)*64 + co)*256 + modeidx;
  float accr[8], acci[8];
  #pragma unroll
  for (int bb = 0; bb < 8; ++bb) { accr[bb] = 0.f; acci[bb] = 0.f; }
  for (int ci = 0; ci < 64; ++ci) {
    float2 wv = wp[(size_t)ci*16384];
    #pragma unroll
    for (int bb = 0; bb < 8; ++bb) {
      float2 xv = xfs[bb][mi][ci];
      accr[bb] += xv.x*wv.x - xv.y*wv.y;
      acci[bb] += xv.x*wv.y + xv.y*wv.x;
    }
  }
  #pragma unroll
  for (int bb = 0; bb < 8; ++bb)
    yf[((size_t)bb*64 + co)*1024 + m] = make_float2(accr[bb], acci[bb]);
}

// ---------------- fused inverse T+H stages (fp16-packed output) ----------------
__global__ __launch_bounds__(256) void k_invTH(const float2* __restrict__ yf,
                                               unsigned* __restrict__ zh16) {
  __shared__ float2 ybuf[1024];
  __shared__ float2 ztb[2][128];
  __shared__ float2 tw128[128];
  int bc = blockIdx.x;
  int b = bc >> 6, c = bc & 63;
  int tid = threadIdx.x;
  for (int u = tid; u < 1024; u += 256) ybuf[u] = yf[(size_t)bc*1024 + u];
  if (tid < 128) {
    float s, co; sincosf(TWO_PI * (float)tid / 128.0f, &s, &co);
    tw128[tid] = make_float2(co, s);
  }
  int tpar = tid >> 7, j = tid & 127;
  __syncthreads();
  for (int tt = 0; tt < 5; ++tt) {
    int t = tt*2 + tpar;
    {
      float sb, cb; sincosf(TWO_PI * (float)t / 10.0f, &sb, &cb);
      float p_r[10], p_i[10];
      p_r[0] = 1.f; p_i[0] = 0.f; p_r[1] = cb; p_i[1] = sb;
      #pragma unroll
      for (int k = 2; k < 10; ++k) {
        p_r[k] = p_r[k-1]*p_r[1] - p_i[k-1]*p_i[1];
        p_i[k] = p_r[k-1]*p_i[1] + p_i[k-1]*p_r[1];
      }
      float zr = 0.f, zi = 0.f;
      #pragma unroll
      for (int kti = 0; kti < 8; ++kti) {
        int kt = (kti < 4) ? kti : kti + 2;
        float2 v = ybuf[kti*128 + j];
        zr += v.x*p_r[kt] - v.y*p_i[kt];
        zi += v.x*p_i[kt] + v.y*p_r[kt];
      }
      ztb[tpar][j] = make_float2(zr*ORTHO_SC, zi*ORTHO_SC);
    }
    __syncthreads();
    {
      int h = j;
      float ar[8], ai[8];
      #pragma unroll
      for (int kw = 0; kw < 8; ++kw) { ar[kw] = 0.f; ai[kw] = 0.f; }
      #pragma unroll
      for (int khi = 0; khi < 16; ++khi) {
        int kh = (khi < 8) ? khi : (112 + khi);
        float2 tw = tw128[(h*kh) & 127];
        #pragma unroll
        for (int kw = 0; kw < 8; ++kw) {
          float2 v = ztb[tpar][khi*8 + kw];
          ar[kw] += v.x*tw.x - v.y*tw.y;
          ai[kw] += v.x*tw.y + v.y*tw.x;
        }
      }
      unsigned* dst = zh16 + (((size_t)(b*10 + t)*128 + h)*64 + c)*8;
      #pragma unroll
      for (int kw = 0; kw < 8; ++kw)
        dst[kw] = (unsigned)f16b(ar[kw]) | ((unsigned)f16b(ai[kw]) << 16);
    }
    __syncthreads();
  }
}

// ---------------- fused inverse-W + skip + GELU (+ next-layer fwdW DFT) ----------------
// T-block uses hi-half twiddles only; Th loaded at use (48 VGPR).
// launch_bounds (256,7): LDS-limited 7 blocks/CU target (was cap=4 -> 51% occ).
__global__ __launch_bounds__(256, 7) void k_invW_mfma(const u16* __restrict__ xTin,
                                                      const unsigned* __restrict__ zh16,
                                                      const u16* __restrict__ swf_l,
                                                      const u16* __restrict__ Tt,
                                                      const u16* __restrict__ Ef,
                                                      const float* __restrict__ skb,
                                                      u16* __restrict__ xTo,
                                                      u16* __restrict__ xw16,
                                                      int do_dft) {
  __shared__ __align__(16) char smem[20480];
  u16* B = (u16*)smem;              // [128][72]
  u16* zAh = (u16*)(smem + 18432);  // [64][16]
  int tid = threadIdx.x;
  int bth = blockIdx.x;
  int lane = tid & 63;
  int wq = tid >> 6;
  int cL = lane & 15;
  int g = lane >> 4;

  {
    const uint4* xsrc = (const uint4*)(xTin + (size_t)bth*8192);
    for (int u = tid; u < 1024; u += 256) {
      int w = u >> 3, c = u & 7;
      ((uint4*)(B + w*72))[c] = xsrc[u];
    }
  }
  {
    const unsigned* zsrc = zh16 + (size_t)bth*512;
    for (int u = tid; u < 512; u += 256) {
      int co = u >> 3, m = u & 7;
      *(unsigned*)(zAh + co*16 + 2*m) = zsrc[u];
    }
  }
  __syncthreads();

  f32x4 acc[4][2];
  #pragma unroll
  for (int s = 0; s < 4; ++s)
    #pragma unroll
    for (int t2 = 0; t2 < 2; ++t2) acc[s][t2] = (f32x4){0.f,0.f,0.f,0.f};

  #pragma unroll
  for (int kb = 0; kb < 2; ++kb) {
    f16x8 Ah[4], Al[4];
    #pragma unroll
    for (int s = 0; s < 4; ++s) {
      Ah[s] = *(const f16x8*)(swf_l + (size_t)(s*2048 + kb*1024 + lane*8));
      Al[s] = *(const f16x8*)(swf_l + (size_t)(s*2048 + kb*1024 + 512 + lane*8));
    }
    #pragma unroll
    for (int t2 = 0; t2 < 2; ++t2) {
      int wrow = wq*32 + t2*16 + cL;
      f16x8 bh = *(const f16x8*)(B + wrow*72 + kb*32 + g*8);
      #pragma unroll
      for (int s = 0; s < 4; ++s) {
        MFMAH(acc[s][t2], Ah[s], bh);
        MFMAH(acc[s][t2], Al[s], bh);
      }
    }
  }
  {
    f16x8 Azh[4];
    f16x8 zero8 = {0,0,0,0,0,0,0,0};
    #pragma unroll
    for (int s = 0; s < 4; ++s)
      Azh[s] = (g < 2) ? *(const f16x8*)(zAh + (s*16 + cL)*16 + g*8) : zero8;
    #pragma unroll
    for (int t2 = 0; t2 < 2; ++t2) {
      int wrow = wq*32 + t2*16 + cL;
      f16x8 th = *(const f16x8*)(Tt + wrow*32 + g*8);
      #pragma unroll
      for (int s = 0; s < 4; ++s) {
        MFMAH(acc[s][t2], Azh[s], th);
      }
    }
  }

  __syncthreads();
  unsigned* out32 = (unsigned*)smem;           // [32][130] u32 (aliases B)
  #pragma unroll
  for (int s = 0; s < 4; ++s) {
    float4 b4 = *(const float4*)(skb + s*16 + g*4);
    float bb[4] = {b4.x, b4.y, b4.z, b4.w};
    #pragma unroll
    for (int t2 = 0; t2 < 2; ++t2) {
      int w = wq*32 + t2*16 + cL;
      u16 gb[4];
      #pragma unroll
      for (int r = 0; r < 4; ++r) {
        float val = acc[s][t2][r] + bb[r];
        gb[r] = f16b(gelu_fast(val));
      }
      out32[(s*8 + g*2 + 0)*130 + w] = (unsigned)gb[0] | ((unsigned)gb[1] << 16);
      out32[(s*8 + g*2 + 1)*130 + w] = (unsigned)gb[2] | ((unsigned)gb[3] << 16);
    }
  }
  __syncthreads();
  {
    uint4* xdst = (uint4*)(xTo + (size_t)bth*8192);
    for (int u = tid; u < 1024; u += 256) {
      int w = u >> 3, c = u & 7;
      unsigned r0 = out32[(c*4 + 0)*130 + w];
      unsigned r1 = out32[(c*4 + 1)*130 + w];
      unsigned r2 = out32[(c*4 + 2)*130 + w];
      unsigned r3 = out32[(c*4 + 3)*130 + w];
      xdst[u] = make_uint4(r0, r1, r2, r3);
    }
  }
  if (do_dft) {
    f32x4 acc2 = (f32x4){0.f,0.f,0.f,0.f};
    int row = wq*8 + (cL >> 1);
    int sh = (cL & 1) * 16;
    #pragma unroll
    for (int kc = 0; kc < 4; ++kc) {
      const unsigned* p = out32 + row*130 + kc*32 + g*8;
      uint2 d0 = *(const uint2*)(p);
      uint2 d1 = *(const uint2*)(p + 2);
      uint2 d2 = *(const uint2*)(p + 4);
      uint2 d3 = *(const uint2*)(p + 6);
      f16x8 a;
      a[0] = __builtin_bit_cast(f16, (u16)(d0.x >> sh));
      a[1] = __builtin_bit_cast(f16, (u16)(d0.y >> sh));
      a[2] = __builtin_bit_cast(f16, (u16)(d1.x >> sh));
      a[3] = __builtin_bit_cast(f16, (u16)(d1.y >> sh));
      a[4] = __builtin_bit_cast(f16, (u16)(d2.x >> sh));
      a[5] = __builtin_bit_cast(f16, (u16)(d2.y >> sh));
      a[6] = __builtin_bit_cast(f16, (u16)(d3.x >> sh));
      a[7] = __builtin_bit_cast(f16, (u16)(d3.y >> sh));
      f16x8 eh = *(const f16x8*)(Ef + (kc*64 + lane)*8);
      f16x8 el = *(const f16x8*)(Ef + 2048 + (kc*64 + lane)*8);
      MFMAH(acc2, a, eh);
      MFMAH(acc2, a, el);
    }
    int h = bth & 127; int bt = bth >> 7; int t = bt % 10, b = bt / 10;
    #pragma unroll
    for (int r = 0; r < 4; ++r) {
      int co = wq*16 + g*4 + r;
      size_t row2 = ((size_t)(b*64 + co)*10 + t)*128 + h;
      xw16[row2*16 + cL] = f16b(acc2[r]);
    }
  }
}

// ---------------- aggregation (K=640) as fp16 MFMA (exact B, direct stores) ----------------
__global__ __launch_bounds__(256) void k_agg_mfma(const u16* __restrict__ xT,
                                                  const u16* __restrict__ awf,
                                                  const float* __restrict__ agg_b,
                                                  float* __restrict__ xa) {
  __shared__ __align__(16) u16 B[128*72];   // 18432 B
  int tid = threadIdx.x;
  int bid = blockIdx.x;
  int h = bid & 127, b = bid >> 7;
  int lane = tid & 63;
  int wq = tid >> 6;
  int cL = lane & 15;
  int g = lane >> 4;

  f32x4 acc[4][2];
  #pragma unroll
  for (int s = 0; s < 4; ++s)
    #pragma unroll
    for (int t2 = 0; t2 < 2; ++t2) acc[s][t2] = (f32x4){0.f,0.f,0.f,0.f};

  for (int t = 0; t < 10; ++t) {
    __syncthreads();
    {
      const uint4* xsrc = (const uint4*)(xT + ((size_t)(b*10 + t)*128 + h)*8192);
      for (int u = tid; u < 1024; u += 256) {
        int w = u >> 3, c = u & 7;
        ((uint4*)(B + w*72))[c] = xsrc[u];
      }
    }
    __syncthreads();
    #pragma unroll
    for (int kc = 0; kc < 2; ++kc) {
      f16x8 Ah[4], Al[4];
      #pragma unroll
      for (int s = 0; s < 4; ++s) {
        const u16* af = awf + (size_t)((s*10 + t)*4 + kc*2)*512;
        Ah[s] = *(const f16x8*)(af + lane*8);
        Al[s] = *(const f16x8*)(af + 512 + lane*8);
      }
      #pragma unroll
      for (int t2 = 0; t2 < 2; ++t2) {
        int wrow = wq*32 + t2*16 + cL;
        f16x8 bh = *(const f16x8*)(B + wrow*72 + kc*32 + g*8);
        #pragma unroll
        for (int s = 0; s < 4; ++s) {
          MFMAH(acc[s][t2], Ah[s], bh);
          MFMAH(acc[s][t2], Al[s], bh);
        }
      }
    }
  }

  #pragma unroll
  for (int s = 0; s < 4; ++s) {
    float4 b4 = *(const float4*)(agg_b + s*16 + g*4);
    float bb[4] = {b4.x, b4.y, b4.z, b4.w};
    #pragma unroll
    for (int t2 = 0; t2 < 2; ++t2) {
      int w = wq*32 + t2*16 + cL;
      #pragma unroll
      for (int r = 0; r < 4; ++r) {
        int co = s*16 + g*4 + r;
        xa[((size_t)(b*64 + co)*128 + h)*128 + w] = acc[s][t2][r] + bb[r];
      }
    }
  }
}

// ---------------- head as split-fp16 MFMA: M=128 o, N=128 w, K=96 ----------------
__global__ __launch_bounds__(256) void k_head_mfma(const float* __restrict__ xa,
                                                   const u16* __restrict__ f1f,
                                                   const float* __restrict__ fc2_w,
                                                   const float* __restrict__ fc2_b,
                                                   float* __restrict__ out) {
  __shared__ __align__(16) u16 B[128*128];   // 32768 B
  __shared__ float w2s[1280];
  int tid = threadIdx.x;
  int bid = blockIdx.x;
  int h = bid & 127, b = bid >> 7;
  for (int i = tid; i < 1280; i += 256) w2s[i] = fc2_w[i];
  for (int u = tid; u < 2048; u += 256) {
    int co = u >> 5, w4 = u & 31;
    float4 v = *(const float4*)(xa + ((size_t)(b*64 + co)*128 + h)*128 + w4*4);
    float vv[4] = {v.x, v.y, v.z, v.w};
    int kg = co >> 3, kj = co & 7;
    #pragma unroll
    for (int jj = 0; jj < 4; ++jj) {
      int w = w4*4 + jj;
      B[w*128 + ((kg ^ (w & 7)) << 3) + kj] = f16b(vv[jj]);
    }
  }
  for (int u = tid; u < 512; u += 256) {
    int w = u & 127, kgo = u >> 7;
    int kg = 8 + kgo;
    u16* dst = &B[w*128 + ((kg ^ (w & 7)) << 3)];
    if (kgo == 0) {
      float gx = -1.f + 2.f*(float)w/127.f;
      float gy = -1.f + 2.f*(float)h/127.f;
      dst[0] = f16b(gx); dst[1] = f16b(gy); dst[2] = f16b(1.f);
      dst[3] = 0; dst[4] = 0; dst[5] = 0; dst[6] = 0; dst[7] = 0;
    } else {
      #pragma unroll
      for (int q = 0; q < 8; ++q) dst[q] = 0;
    }
  }
  __syncthreads();

  int lane = tid & 63, wq = tid >> 6, cL = lane & 15, g = lane >> 4;
  f32x4 acc[8][2];
  #pragma unroll
  for (int s = 0; s < 8; ++s)
    #pragma unroll
    for (int t2 = 0; t2 < 2; ++t2) acc[s][t2] = (f32x4){0.f,0.f,0.f,0.f};

  #pragma unroll
  for (int kc = 0; kc < 3; ++kc) {
    f16x8 bfr[2];
    #pragma unroll
    for (int t2 = 0; t2 < 2; ++t2) {
      int wrow = wq*32 + t2*16 + cL;
      int kg = kc*4 + g;
      bfr[t2] = *(const f16x8*)(&B[wrow*128 + ((kg ^ (wrow & 7)) << 3)]);
    }
    #pragma unroll
    for (int s = 0; s < 8; ++s) {
      f16x8 Ah = *(const f16x8*)(f1f + (size_t)(((s*3 + kc)*2 + 0)*64 + lane)*8);
      f16x8 Al = *(const f16x8*)(f1f + (size_t)(((s*3 + kc)*2 + 1)*64 + lane)*8);
      #pragma unroll
      for (int t2 = 0; t2 < 2; ++t2) {
        MFMAH(acc[s][t2], Ah, bfr[t2]);
        MFMAH(acc[s][t2], Al, bfr[t2]);
      }
    }
  }

  float o2[2][10];
  #pragma unroll
  for (int t2 = 0; t2 < 2; ++t2)
    #pragma unroll
    for (int j = 0; j < 10; ++j) o2[t2][j] = 0.f;
  #pragma unroll
  for (int s = 0; s < 8; ++s) {
    #pragma unroll
    for (int t2 = 0; t2 < 2; ++t2) {
      #pragma unroll
      for (int r = 0; r < 4; ++r) {
        int o = s*16 + g*4 + r;
        float gl = gelu_fast(acc[s][t2][r]);
        #pragma unroll
        for (int j = 0; j < 10; ++j) o2[t2][j] += gl * w2s[o*10 + j];
      }
    }
  }
  #pragma unroll
  for (int t2 = 0; t2 < 2; ++t2)
    #pragma unroll
    for (int j = 0; j < 10; ++j) {
      float v = o2[t2][j];
      v += __shfl_xor(v, 16, 64);
      v += __shfl_xor(v, 32, 64);
      o2[t2][j] = v;
    }
  if (g == 0) {
    #pragma unroll
    for (int t2 = 0; t2 < 2; ++t2) {
      int w = wq*32 + t2*16 + cL;
      float* dst = out + ((size_t)bid*128 + w)*10;
      float tot[10];
      #pragma unroll
      for (int j = 0; j < 10; ++j) tot[j] = o2[t2][j] + fc2_b[j];
      #pragma unroll
      for (int k = 0; k < 5; ++k) dst[k] = tot[2*k];
      #pragma unroll
      for (int k = 0; k < 5; ++k) {
        float sv = tot[2*k+1];
        float sp = fmaxf(sv, 0.f) + log1pf(expf(-fabsf(sv)));
        dst[5 + k] = sp + 1e-4f;
      }
    }
  }
}

extern "C" void kernel_launch(void* const* d_in, const int* in_sizes, int n_in,
                              void* d_out, int out_size, void* d_ws, size_t ws_size,
                              hipStream_t stream) {
  const float* frames = (const float*)d_in[0];
  const float* times  = (const float*)d_in[1];
  const float* lift_w = (const float*)d_in[2];
  const float* lift_b = (const float*)d_in[3];
  const float* spec_w = (const float*)d_in[4];
  const float* skip_w = (const float*)d_in[5];
  const float* skip_b = (const float*)d_in[6];
  const float* agg_w  = (const float*)d_in[7];
  const float* agg_b  = (const float*)d_in[8];
  const float* fc1_w  = (const float*)d_in[9];
  const float* fc1_b  = (const float*)d_in[10];
  const float* fc2_w  = (const float*)d_in[11];
  const float* fc2_b  = (const float*)d_in[12];
  float* out = (float*)d_out;
  char* ws = (char*)d_ws;

  size_t off = 0;
  u16*      xT  = (u16*)(ws + off);      off += (size_t)10240*8192*2;       // 167,772,160
  u16*      xw16= (u16*)(ws + off);      off += (size_t)655360*16*2;        // 20,971,520
  float2*   xf  = (float2*)(ws + off);   off += (size_t)8*1024*64*8;        // 4,194,304
  float2*   yf  = (float2*)(ws + off);   off += (size_t)8*1024*64*8;        // 4,194,304
  unsigned* zh16= (unsigned*)(ws + off); off += (size_t)10240*512*4;        // 20,971,520
  float*    xa  = (float*)(ws + off);    off += (size_t)8*64*128*128*4;     // 33,554,432
  u16*      swf = (u16*)(ws + off);      off += (size_t)32768*2;            // 65,536
  u16*      awf = (u16*)(ws + off);      off += (size_t)81920*2;            // 163,840
  u16*      Tt  = (u16*)(ws + off);      off += (size_t)8192*2;             // 16,384
  float2*   twf = (float2*)(ws + off);   off += (size_t)1024*8;             // 8,192
  u16*      Ef  = (u16*)(ws + off);      off += (size_t)4096*2;             // 8,192
  u16*      f1f = (u16*)(ws + off);      off += (size_t)24576*2;            // 49,152

  k_prep2<<<588, 256, 0, stream>>>(skip_w, agg_w, fc1_w, fc1_b,
                                   swf, awf, Tt, twf, Ef, f1f);
  k_lift_fwdW<<<10240, 128, 0, stream>>>(frames, times, lift_w, lift_b, twf, xT, xw16);

  for (int l = 0; l < 4; ++l) {
    k_fwdHT<<<512, 256, 0, stream>>>((const unsigned*)xw16, xf);
    k_mix<<<256, 256, 0, stream>>>(xf, spec_w + (size_t)l*4*64*64*256*2, yf);
    k_invTH<<<512, 256, 0, stream>>>(yf, zh16);
    k_invW_mfma<<<10240, 256, 0, stream>>>(xT, zh16, swf + (size_t)l*8192, Tt, Ef,
                                           skip_b + l*64, xT, xw16, (l < 3) ? 1 : 0);
  }
  k_agg_mfma<<<1024, 256, 0, stream>>>(xT, awf, agg_b, xa);
  k_head_mfma<<<1024, 256, 0, stream>>>(xa, f1f, fc2_w, fc2_b, out);
}

// Round 20
// 937.049 us; speedup vs baseline: 1.3333x; 1.3333x over previous
//
#include <hip/hip_runtime.h>
#include <math.h>

// FNO3d forward. B=8,T=10,H=128,W=128, C=64, NL=4, modes kt8 kh16 kw8.
// x stored FP16, layout xT[(b*10+t)*128+h][w][ci].
// Round 20: r18 + invW launch_bounds (256,5). Measured VGPR-cap series
// ((256,4)->64, (256,6)->40, (256,7)->36) shows per-SIMD pool = 256 regs;
// 48-VGPR kernel supports max 5 waves/SIMD. cap(5)=51 >= 48 -> no spill.

#define TWO_PI 6.2831853071795864769f
#define ORTHO_SC 2.4705294220065465e-3f  // 1/sqrt(10*128*128)

typedef unsigned short u16;
typedef _Float16 f16;
typedef __attribute__((ext_vector_type(8))) _Float16 f16x8;
typedef __attribute__((ext_vector_type(4))) float f32x4;

#define MFMAH(acc, a, b) acc = __builtin_amdgcn_mfma_f32_16x16x32_f16(a, b, acc, 0, 0, 0)

__device__ __forceinline__ u16 f16b(float v) {
  f16 h = (f16)v;
  return __builtin_bit_cast(u16, h);
}
__device__ __forceinline__ float f16lo(float v) {  // v - fp16(v)
  f16 h = (f16)v;
  return v - (float)h;
}
__device__ __forceinline__ float f16f(u16 b) {
  return (float)__builtin_bit_cast(f16, b);
}
// tanh-approx GELU via exp2 (~9 VALU ops)
__device__ __forceinline__ float gelu_fast(float x) {
  float u = 0.7978845608f * (x + 0.044715f * x * x * x);
  float a = fminf(u * 2.885390082f, 30.0f);
  float e = __builtin_exp2f(a);
  return x * e * __builtin_amdgcn_rcpf(e + 1.0f);
}

// ---------------- prep: A-fragments (split fp16) + twiddle tables ----------------
// swf: [layer4][strip4][kb2][hl2][lane64][8]
// awf: [strip4][t10][kc2][hl2][lane64][8]
// Tt : [hl2][w128][kk32]
// twf: [w128][k8] float2
// Ef : [hl2][kc4][lane64][8]
// f1f: [strip8][kc3][hl2][lane64][8]  (head fc1^T; k=66 row = fc1_b)
__global__ __launch_bounds__(256) void k_prep2(const float* __restrict__ skip_w,
                                               const float* __restrict__ agg_w,
                                               const float* __restrict__ fc1_w,
                                               const float* __restrict__ fc1_b,
                                               u16* __restrict__ swf,
                                               u16* __restrict__ awf,
                                               u16* __restrict__ Tt,
                                               float2* __restrict__ twf,
                                               u16* __restrict__ Ef,
                                               u16* __restrict__ f1f) {
  int e = blockIdx.x*256 + threadIdx.x;
  if (e < 32768) {
    int j = e & 7, lane = (e >> 3) & 63, half = (e >> 9) & 1, ks = (e >> 10) & 1;
    int strip = (e >> 11) & 3, layer = e >> 13;
    int co = strip*16 + (lane & 15);
    int ci = ks*32 + (lane >> 4)*8 + j;
    float v = skip_w[((size_t)(layer*64) + co)*64 + ci];
    swf[e] = half ? f16b(f16lo(v)) : f16b(v);
  } else if (e < 114688) {
    int ee = e - 32768;
    int j = ee & 7, lane = (ee >> 3) & 63;
    int v9 = ee >> 9;
    int half = v9 & 1; v9 >>= 1;
    int ks = v9 & 1; v9 >>= 1;
    int t = v9 % 10, strip = v9 / 10;
    int co = strip*16 + (lane & 15);
    int ci = ks*32 + (lane >> 4)*8 + j;
    float v = agg_w[((size_t)co*64 + ci)*10 + t];
    awf[ee] = half ? f16b(f16lo(v)) : f16b(v);
  } else if (e < 122880) {
    int ee = e - 114688;
    int half = ee >> 12, r = ee & 4095, w = r >> 5, kk = r & 31;
    int m = kk >> 1;
    float val;
    if (kk >= 16) val = 0.f;
    else if (kk == 0) val = 1.f;
    else if (kk == 1) val = 0.f;
    else {
      float th = TWO_PI * (float)m * (float)w / 128.0f;
      val = (kk & 1) ? (-2.f*sinf(th)) : (2.f*cosf(th));
    }
    Tt[ee] = half ? f16b(f16lo(val)) : f16b(val);
  } else if (e < 123904) {
    int ee = e - 122880;
    int w = ee >> 3, k = ee & 7;
    float th = TWO_PI * (float)k * (float)w / 128.0f;
    twf[ee] = make_float2(cosf(th), -sinf(th));
  } else if (e < 125952) {
    int ee = e - 123904;
    int j = ee & 7, lane = (ee >> 3) & 63, kc = ee >> 9;
    int n = lane & 15, g = lane >> 4;
    int w = kc*32 + g*8 + j;
    int k = n >> 1;
    float th = TWO_PI * (float)k * (float)w / 128.0f;
    float val = (n & 1) ? (-sinf(th)) : cosf(th);
    Ef[ee] = f16b(val);
    Ef[2048 + ee] = f16b(f16lo(val));
  } else if (e < 150528) {
    int ee = e - 125952;
    int j = ee & 7, lane = (ee >> 3) & 63, hl = (ee >> 9) & 1;
    int rest = ee >> 10;         // 0..23
    int kc = rest % 3, strip = rest / 3;
    int o = strip*16 + (lane & 15);
    int k = kc*32 + (lane >> 4)*8 + j;
    float v;
    if (k < 66) v = fc1_w[(size_t)k*128 + o];
    else if (k == 66) v = fc1_b[o];
    else v = 0.f;
    f1f[ee] = hl ? f16b(f16lo(v)) : f16b(v);
  }
}

// ---------------- fused lift + layer-0 forward-W DFT (fp16 xw) ----------------
__global__ __launch_bounds__(128) void k_lift_fwdW(const float* __restrict__ frames,
                                                   const float* __restrict__ times,
                                                   const float* __restrict__ lift_w,
                                                   const float* __restrict__ lift_b,
                                                   const float2* __restrict__ twf,
                                                   u16* __restrict__ xT,
                                                   u16* __restrict__ xw16) {
  __shared__ u16 xs[64][130];
  __shared__ float2 tws[128][8];
  __shared__ float fr[128];
  __shared__ float lw0[64], lw1a[64];
  int bth = blockIdx.x;
  int h = bth & 127; int bt = bth >> 7; int t = bt % 10, b = bt / 10;
  int tid = threadIdx.x;
  for (int i = tid; i < 1024; i += 128) tws[i >> 3][i & 7] = twf[i];
  float tv = times[b*10 + t];
  fr[tid] = frames[((size_t)(b*10 + t)*128 + h)*128 + tid];
  if (tid < 64) { lw0[tid] = lift_w[2*tid]; lw1a[tid] = lift_w[2*tid+1]*tv + lift_b[tid]; }
  __syncthreads();
  {
    int w = tid;
    float f = fr[w];
    unsigned pk[32];
    #pragma unroll
    for (int q = 0; q < 32; ++q) {
      float v0 = f*lw0[2*q] + lw1a[2*q];
      float v1 = f*lw0[2*q+1] + lw1a[2*q+1];
      u16 h0 = f16b(v0), h1 = f16b(v1);
      xs[2*q][w] = h0; xs[2*q+1][w] = h1;
      pk[q] = (unsigned)h0 | ((unsigned)h1 << 16);
    }
    uint4* d4 = (uint4*)(xT + (size_t)bth*8192 + w*64);
    #pragma unroll
    for (int q = 0; q < 8; ++q)
      d4[q] = make_uint4(pk[4*q], pk[4*q+1], pk[4*q+2], pk[4*q+3]);
  }
  __syncthreads();
  {
    int lane = tid & 63, wv = tid >> 6;
    float ar[4] = {0,0,0,0}, ai[4] = {0,0,0,0};
    for (int w2 = 0; w2 < 128; ++w2) {
      float xu = f16f(xs[lane][w2]);
      #pragma unroll
      for (int kk = 0; kk < 4; ++kk) {
        float2 ew = tws[w2][wv*4 + kk];
        ar[kk] += xu*ew.x; ai[kk] += xu*ew.y;
      }
    }
    size_t row = ((size_t)(b*64 + lane)*10 + t)*128 + h;
    unsigned p0 = (unsigned)f16b(ar[0]) | ((unsigned)f16b(ai[0]) << 16);
    unsigned p1 = (unsigned)f16b(ar[1]) | ((unsigned)f16b(ai[1]) << 16);
    unsigned p2 = (unsigned)f16b(ar[2]) | ((unsigned)f16b(ai[2]) << 16);
    unsigned p3 = (unsigned)f16b(ar[3]) | ((unsigned)f16b(ai[3]) << 16);
    *(uint4*)(xw16 + row*16 + wv*8) = make_uint4(p0, p1, p2, p3);
  }
}

// ---------------- fused forward H+T stages (fp16 xw input) ----------------
__global__ __launch_bounds__(256) void k_fwdHT(const unsigned* __restrict__ xw32,
                                               float2* __restrict__ xf) {
  __shared__ unsigned tile[2][1024];
  __shared__ float2 parts1[1024];
  __shared__ float2 tw128[128];
  int bc = blockIdx.x;
  int b = bc >> 6, c = bc & 63;
  int tid = threadIdx.x;
  if (tid < 128) {
    float s, co; sincosf(TWO_PI * (float)tid / 128.0f, &s, &co);
    tw128[tid] = make_float2(co, -s);
  }
  int tpar = tid >> 7, j = tid & 127;
  int khi = j >> 3, kwi = j & 7;
  int kh = (khi < 8) ? khi : (112 + khi);
  float accr[8], acci[8];
  #pragma unroll
  for (int k = 0; k < 8; ++k) { accr[k] = 0.f; acci[k] = 0.f; }
  for (int tt = 0; tt < 5; ++tt) {
    __syncthreads();
    for (int u = tid; u < 2048; u += 256) {
      int tg = u >> 10, idx = u & 1023;
      tile[tg][idx] = xw32[((size_t)bc*10 + tg*5 + tt)*1024 + idx];
    }
    __syncthreads();
    float xr = 0.f, xi = 0.f;
    for (int h = 0; h < 128; ++h) {
      unsigned uv = tile[tpar][h*8 + kwi];
      float vx = f16f((u16)uv);
      float vy = f16f((u16)(uv >> 16));
      float2 tw = tw128[(h*kh) & 127];
      xr += vx*tw.x - vy*tw.y;
      xi += vx*tw.y + vy*tw.x;
    }
    int t = tpar*5 + tt;
    float sb, cb; sincosf(TWO_PI * (float)t / 10.0f, &sb, &cb);
    float p_r[10], p_i[10];
    p_r[0] = 1.f; p_i[0] = 0.f; p_r[1] = cb; p_i[1] = -sb;
    #pragma unroll
    for (int k = 2; k < 10; ++k) {
      p_r[k] = p_r[k-1]*p_r[1] - p_i[k-1]*p_i[1];
      p_i[k] = p_r[k-1]*p_i[1] + p_i[k-1]*p_r[1];
    }
    #pragma unroll
    for (int kti = 0; kti < 8; ++kti) {
      int kt = (kti < 4) ? kti : kti + 2;
      accr[kti] += xr*p_r[kt] - xi*p_i[kt];
      acci[kti] += xr*p_i[kt] + xi*p_r[kt];
    }
  }
  __syncthreads();
  if (tpar == 1) {
    #pragma unroll
    for (int kti = 0; kti < 8; ++kti)
      parts1[j*8 + kti] = make_float2(accr[kti], acci[kti]);
  }
  __syncthreads();
  if (tpar == 0) {
    #pragma unroll
    for (int kti = 0; kti < 8; ++kti) {
      float2 bq = parts1[j*8 + kti];
      xf[((size_t)b*1024 + kti*128 + j)*64 + c] =
          make_float2((accr[kti] + bq.x)*ORTHO_SC, (acci[kti] + bq.y)*ORTHO_SC);
    }
  }
}

// ---------------- channel mix (reads spec_w original layout directly) ----------------
__global__ __launch_bounds__(256) void k_mix(const float2* __restrict__ xf,
                                             const float* __restrict__ spec_w_l,
                                             float2* __restrict__ yf) {
  __shared__ float2 xfs[8][4][64];
  int m0 = blockIdx.x * 4;
  for (int i = threadIdx.x; i < 2048; i += 256) {
    int bb = i >> 8, mi = (i >> 6) & 3, ci = i & 63;
    xfs[bb][mi][ci] = xf[((size_t)bb*1024 + m0 + mi)*64 + ci];
  }
  __syncthreads();
  int co = threadIdx.x & 63, mi = threadIdx.x >> 6;
  int m = m0 + mi;
  int kti = m >> 7, khi = (m >> 3) & 15, kwi = m & 7;
  int q = ((kti >= 4) ? 2 : 0) + ((khi >= 8) ? 1 : 0);
  int modeidx = ((kti & 3)*8 + (khi & 7))*8 + kwi;
  const float2* wp = (const float2*)spec_w_l
                     + ((size_t)(q*64)*64 + co)*256 + modeidx;
  float accr[8], acci[8];
  #pragma unroll
  for (int bb = 0; bb < 8; ++bb) { accr[bb] = 0.f; acci[bb] = 0.f; }
  for (int ci = 0; ci < 64; ++ci) {
    float2 wv = wp[(size_t)ci*16384];
    #pragma unroll
    for (int bb = 0; bb < 8; ++bb) {
      float2 xv = xfs[bb][mi][ci];
      accr[bb] += xv.x*wv.x - xv.y*wv.y;
      acci[bb] += xv.x*wv.y + xv.y*wv.x;
    }
  }
  #pragma unroll
  for (int bb = 0; bb < 8; ++bb)
    yf[((size_t)bb*64 + co)*1024 + m] = make_float2(accr[bb], acci[bb]);
}

// ---------------- fused inverse T+H stages (fp16-packed output) ----------------
__global__ __launch_bounds__(256) void k_invTH(const float2* __restrict__ yf,
                                               unsigned* __restrict__ zh16) {
  __shared__ float2 ybuf[1024];
  __shared__ float2 ztb[2][128];
  __shared__ float2 tw128[128];
  int bc = blockIdx.x;
  int b = bc >> 6, c = bc & 63;
  int tid = threadIdx.x;
  for (int u = tid; u < 1024; u += 256) ybuf[u] = yf[(size_t)bc*1024 + u];
  if (tid < 128) {
    float s, co; sincosf(TWO_PI * (float)tid / 128.0f, &s, &co);
    tw128[tid] = make_float2(co, s);
  }
  int tpar = tid >> 7, j = tid & 127;
  __syncthreads();
  for (int tt = 0; tt < 5; ++tt) {
    int t = tt*2 + tpar;
    {
      float sb, cb; sincosf(TWO_PI * (float)t / 10.0f, &sb, &cb);
      float p_r[10], p_i[10];
      p_r[0] = 1.f; p_i[0] = 0.f; p_r[1] = cb; p_i[1] = sb;
      #pragma unroll
      for (int k = 2; k < 10; ++k) {
        p_r[k] = p_r[k-1]*p_r[1] - p_i[k-1]*p_i[1];
        p_i[k] = p_r[k-1]*p_i[1] + p_i[k-1]*p_r[1];
      }
      float zr = 0.f, zi = 0.f;
      #pragma unroll
      for (int kti = 0; kti < 8; ++kti) {
        int kt = (kti < 4) ? kti : kti + 2;
        float2 v = ybuf[kti*128 + j];
        zr += v.x*p_r[kt] - v.y*p_i[kt];
        zi += v.x*p_i[kt] + v.y*p_r[kt];
      }
      ztb[tpar][j] = make_float2(zr*ORTHO_SC, zi*ORTHO_SC);
    }
    __syncthreads();
    {
      int h = j;
      float ar[8], ai[8];
      #pragma unroll
      for (int kw = 0; kw < 8; ++kw) { ar[kw] = 0.f; ai[kw] = 0.f; }
      #pragma unroll
      for (int khi = 0; khi < 16; ++khi) {
        int kh = (khi < 8) ? khi : (112 + khi);
        float2 tw = tw128[(h*kh) & 127];
        #pragma unroll
        for (int kw = 0; kw < 8; ++kw) {
          float2 v = ztb[tpar][khi*8 + kw];
          ar[kw] += v.x*tw.x - v.y*tw.y;
          ai[kw] += v.x*tw.y + v.y*tw.x;
        }
      }
      unsigned* dst = zh16 + (((size_t)(b*10 + t)*128 + h)*64 + c)*8;
      #pragma unroll
      for (int kw = 0; kw < 8; ++kw)
        dst[kw] = (unsigned)f16b(ar[kw]) | ((unsigned)f16b(ai[kw]) << 16);
    }
    __syncthreads();
  }
}

// ---------------- fused inverse-W + skip + GELU (+ next-layer fwdW DFT) ----------------
// T-block uses hi-half twiddles only; Th loaded at use (48 VGPR).
// launch_bounds (256,5): max legal occupancy for 48 VGPR (pool=256/SIMD).
__global__ __launch_bounds__(256, 5) void k_invW_mfma(const u16* __restrict__ xTin,
                                                      const unsigned* __restrict__ zh16,
                                                      const u16* __restrict__ swf_l,
                                                      const u16* __restrict__ Tt,
                                                      const u16* __restrict__ Ef,
                                                      const float* __restrict__ skb,
                                                      u16* __restrict__ xTo,
                                                      u16* __restrict__ xw16,
                                                      int do_dft) {
  __shared__ __align__(16) char smem[20480];
  u16* B = (u16*)smem;              // [128][72]
  u16* zAh = (u16*)(smem + 18432);  // [64][16]
  int tid = threadIdx.x;
  int bth = blockIdx.x;
  int lane = tid & 63;
  int wq = tid >> 6;
  int cL = lane & 15;
  int g = lane >> 4;

  {
    const uint4* xsrc = (const uint4*)(xTin + (size_t)bth*8192);
    for (int u = tid; u < 1024; u += 256) {
      int w = u >> 3, c = u & 7;
      ((uint4*)(B + w*72))[c] = xsrc[u];
    }
  }
  {
    const unsigned* zsrc = zh16 + (size_t)bth*512;
    for (int u = tid; u < 512; u += 256) {
      int co = u >> 3, m = u & 7;
      *(unsigned*)(zAh + co*16 + 2*m) = zsrc[u];
    }
  }
  __syncthreads();

  f32x4 acc[4][2];
  #pragma unroll
  for (int s = 0; s < 4; ++s)
    #pragma unroll
    for (int t2 = 0; t2 < 2; ++t2) acc[s][t2] = (f32x4){0.f,0.f,0.f,0.f};

  #pragma unroll
  for (int kb = 0; kb < 2; ++kb) {
    f16x8 Ah[4], Al[4];
    #pragma unroll
    for (int s = 0; s < 4; ++s) {
      Ah[s] = *(const f16x8*)(swf_l + (size_t)(s*2048 + kb*1024 + lane*8));
      Al[s] = *(const f16x8*)(swf_l + (size_t)(s*2048 + kb*1024 + 512 + lane*8));
    }
    #pragma unroll
    for (int t2 = 0; t2 < 2; ++t2) {
      int wrow = wq*32 + t2*16 + cL;
      f16x8 bh = *(const f16x8*)(B + wrow*72 + kb*32 + g*8);
      #pragma unroll
      for (int s = 0; s < 4; ++s) {
        MFMAH(acc[s][t2], Ah[s], bh);
        MFMAH(acc[s][t2], Al[s], bh);
      }
    }
  }
  {
    f16x8 Azh[4];
    f16x8 zero8 = {0,0,0,0,0,0,0,0};
    #pragma unroll
    for (int s = 0; s < 4; ++s)
      Azh[s] = (g < 2) ? *(const f16x8*)(zAh + (s*16 + cL)*16 + g*8) : zero8;
    #pragma unroll
    for (int t2 = 0; t2 < 2; ++t2) {
      int wrow = wq*32 + t2*16 + cL;
      f16x8 th = *(const f16x8*)(Tt + wrow*32 + g*8);
      #pragma unroll
      for (int s = 0; s < 4; ++s) {
        MFMAH(acc[s][t2], Azh[s], th);
      }
    }
  }

  __syncthreads();
  unsigned* out32 = (unsigned*)smem;           // [32][130] u32 (aliases B)
  #pragma unroll
  for (int s = 0; s < 4; ++s) {
    float4 b4 = *(const float4*)(skb + s*16 + g*4);
    float bb[4] = {b4.x, b4.y, b4.z, b4.w};
    #pragma unroll
    for (int t2 = 0; t2 < 2; ++t2) {
      int w = wq*32 + t2*16 + cL;
      u16 gb[4];
      #pragma unroll
      for (int r = 0; r < 4; ++r) {
        float val = acc[s][t2][r] + bb[r];
        gb[r] = f16b(gelu_fast(val));
      }
      out32[(s*8 + g*2 + 0)*130 + w] = (unsigned)gb[0] | ((unsigned)gb[1] << 16);
      out32[(s*8 + g*2 + 1)*130 + w] = (unsigned)gb[2] | ((unsigned)gb[3] << 16);
    }
  }
  __syncthreads();
  {
    uint4* xdst = (uint4*)(xTo + (size_t)bth*8192);
    for (int u = tid; u < 1024; u += 256) {
      int w = u >> 3, c = u & 7;
      unsigned r0 = out32[(c*4 + 0)*130 + w];
      unsigned r1 = out32[(c*4 + 1)*130 + w];
      unsigned r2 = out32[(c*4 + 2)*130 + w];
      unsigned r3 = out32[(c*4 + 3)*130 + w];
      xdst[u] = make_uint4(r0, r1, r2, r3);
    }
  }
  if (do_dft) {
    f32x4 acc2 = (f32x4){0.f,0.f,0.f,0.f};
    int row = wq*8 + (cL >> 1);
    int sh = (cL & 1) * 16;
    #pragma unroll
    for (int kc = 0; kc < 4; ++kc) {
      const unsigned* p = out32 + row*130 + kc*32 + g*8;
      uint2 d0 = *(const uint2*)(p);
      uint2 d1 = *(const uint2*)(p + 2);
      uint2 d2 = *(const uint2*)(p + 4);
      uint2 d3 = *(const uint2*)(p + 6);
      f16x8 a;
      a[0] = __builtin_bit_cast(f16, (u16)(d0.x >> sh));
      a[1] = __builtin_bit_cast(f16, (u16)(d0.y >> sh));
      a[2] = __builtin_bit_cast(f16, (u16)(d1.x >> sh));
      a[3] = __builtin_bit_cast(f16, (u16)(d1.y >> sh));
      a[4] = __builtin_bit_cast(f16, (u16)(d2.x >> sh));
      a[5] = __builtin_bit_cast(f16, (u16)(d2.y >> sh));
      a[6] = __builtin_bit_cast(f16, (u16)(d3.x >> sh));
      a[7] = __builtin_bit_cast(f16, (u16)(d3.y >> sh));
      f16x8 eh = *(const f16x8*)(Ef + (kc*64 + lane)*8);
      f16x8 el = *(const f16x8*)(Ef + 2048 + (kc*64 + lane)*8);
      MFMAH(acc2, a, eh);
      MFMAH(acc2, a, el);
    }
    int h = bth & 127; int bt = bth >> 7; int t = bt % 10, b = bt / 10;
    #pragma unroll
    for (int r = 0; r < 4; ++r) {
      int co = wq*16 + g*4 + r;
      size_t row2 = ((size_t)(b*64 + co)*10 + t)*128 + h;
      xw16[row2*16 + cL] = f16b(acc2[r]);
    }
  }
}

// ---------------- aggregation (K=640) as fp16 MFMA (exact B, direct stores) ----------------
__global__ __launch_bounds__(256) void k_agg_mfma(const u16* __restrict__ xT,
                                                  const u16* __restrict__ awf,
                                                  const float* __restrict__ agg_b,
                                                  float* __restrict__ xa) {
  __shared__ __align__(16) u16 B[128*72];   // 18432 B
  int tid = threadIdx.x;
  int bid = blockIdx.x;
  int h = bid & 127, b = bid >> 7;
  int lane = tid & 63;
  int wq = tid >> 6;
  int cL = lane & 15;
  int g = lane >> 4;

  f32x4 acc[4][2];
  #pragma unroll
  for (int s = 0; s < 4; ++s)
    #pragma unroll
    for (int t2 = 0; t2 < 2; ++t2) acc[s][t2] = (f32x4){0.f,0.f,0.f,0.f};

  for (int t = 0; t < 10; ++t) {
    __syncthreads();
    {
      const uint4* xsrc = (const uint4*)(xT + ((size_t)(b*10 + t)*128 + h)*8192);
      for (int u = tid; u < 1024; u += 256) {
        int w = u >> 3, c = u & 7;
        ((uint4*)(B + w*72))[c] = xsrc[u];
      }
    }
    __syncthreads();
    #pragma unroll
    for (int kc = 0; kc < 2; ++kc) {
      f16x8 Ah[4], Al[4];
      #pragma unroll
      for (int s = 0; s < 4; ++s) {
        const u16* af = awf + (size_t)((s*10 + t)*4 + kc*2)*512;
        Ah[s] = *(const f16x8*)(af + lane*8);
        Al[s] = *(const f16x8*)(af + 512 + lane*8);
      }
      #pragma unroll
      for (int t2 = 0; t2 < 2; ++t2) {
        int wrow = wq*32 + t2*16 + cL;
        f16x8 bh = *(const f16x8*)(B + wrow*72 + kc*32 + g*8);
        #pragma unroll
        for (int s = 0; s < 4; ++s) {
          MFMAH(acc[s][t2], Ah[s], bh);
          MFMAH(acc[s][t2], Al[s], bh);
        }
      }
    }
  }

  #pragma unroll
  for (int s = 0; s < 4; ++s) {
    float4 b4 = *(const float4*)(agg_b + s*16 + g*4);
    float bb[4] = {b4.x, b4.y, b4.z, b4.w};
    #pragma unroll
    for (int t2 = 0; t2 < 2; ++t2) {
      int w = wq*32 + t2*16 + cL;
      #pragma unroll
      for (int r = 0; r < 4; ++r) {
        int co = s*16 + g*4 + r;
        xa[((size_t)(b*64 + co)*128 + h)*128 + w] = acc[s][t2][r] + bb[r];
      }
    }
  }
}

// ---------------- head as split-fp16 MFMA: M=128 o, N=128 w, K=96 ----------------
__global__ __launch_bounds__(256) void k_head_mfma(const float* __restrict__ xa,
                                                   const u16* __restrict__ f1f,
                                                   const float* __restrict__ fc2_w,
                                                   const float* __restrict__ fc2_b,
                                                   float* __restrict__ out) {
  __shared__ __align__(16) u16 B[128*128];   // 32768 B
  __shared__ float w2s[1280];
  int tid = threadIdx.x;
  int bid = blockIdx.x;
  int h = bid & 127, b = bid >> 7;
  for (int i = tid; i < 1280; i += 256) w2s[i] = fc2_w[i];
  for (int u = tid; u < 2048; u += 256) {
    int co = u >> 5, w4 = u & 31;
    float4 v = *(const float4*)(xa + ((size_t)(b*64 + co)*128 + h)*128 + w4*4);
    float vv[4] = {v.x, v.y, v.z, v.w};
    int kg = co >> 3, kj = co & 7;
    #pragma unroll
    for (int jj = 0; jj < 4; ++jj) {
      int w = w4*4 + jj;
      B[w*128 + ((kg ^ (w & 7)) << 3) + kj] = f16b(vv[jj]);
    }
  }
  for (int u = tid; u < 512; u += 256) {
    int w = u & 127, kgo = u >> 7;
    int kg = 8 + kgo;
    u16* dst = &B[w*128 + ((kg ^ (w & 7)) << 3)];
    if (kgo == 0) {
      float gx = -1.f + 2.f*(float)w/127.f;
      float gy = -1.f + 2.f*(float)h/127.f;
      dst[0] = f16b(gx); dst[1] = f16b(gy); dst[2] = f16b(1.f);
      dst[3] = 0; dst[4] = 0; dst[5] = 0; dst[6] = 0; dst[7] = 0;
    } else {
      #pragma unroll
      for (int q = 0; q < 8; ++q) dst[q] = 0;
    }
  }
  __syncthreads();

  int lane = tid & 63, wq = tid >> 6, cL = lane & 15, g = lane >> 4;
  f32x4 acc[8][2];
  #pragma unroll
  for (int s = 0; s < 8; ++s)
    #pragma unroll
    for (int t2 = 0; t2 < 2; ++t2) acc[s][t2] = (f32x4){0.f,0.f,0.f,0.f};

  #pragma unroll
  for (int kc = 0; kc < 3; ++kc) {
    f16x8 bfr[2];
    #pragma unroll
    for (int t2 = 0; t2 < 2; ++t2) {
      int wrow = wq*32 + t2*16 + cL;
      int kg = kc*4 + g;
      bfr[t2] = *(const f16x8*)(&B[wrow*128 + ((kg ^ (wrow & 7)) << 3)]);
    }
    #pragma unroll
    for (int s = 0; s < 8; ++s) {
      f16x8 Ah = *(const f16x8*)(f1f + (size_t)(((s*3 + kc)*2 + 0)*64 + lane)*8);
      f16x8 Al = *(const f16x8*)(f1f + (size_t)(((s*3 + kc)*2 + 1)*64 + lane)*8);
      #pragma unroll
      for (int t2 = 0; t2 < 2; ++t2) {
        MFMAH(acc[s][t2], Ah, bfr[t2]);
        MFMAH(acc[s][t2], Al, bfr[t2]);
      }
    }
  }

  float o2[2][10];
  #pragma unroll
  for (int t2 = 0; t2 < 2; ++t2)
    #pragma unroll
    for (int j = 0; j < 10; ++j) o2[t2][j] = 0.f;
  #pragma unroll
  for (int s = 0; s < 8; ++s) {
    #pragma unroll
    for (int t2 = 0; t2 < 2; ++t2) {
      #pragma unroll
      for (int r = 0; r < 4; ++r) {
        int o = s*16 + g*4 + r;
        float gl = gelu_fast(acc[s][t2][r]);
        #pragma unroll
        for (int j = 0; j < 10; ++j) o2[t2][j] += gl * w2s[o*10 + j];
      }
    }
  }
  #pragma unroll
  for (int t2 = 0; t2 < 2; ++t2)
    #pragma unroll
    for (int j = 0; j < 10; ++j) {
      float v = o2[t2][j];
      v += __shfl_xor(v, 16, 64);
      v += __shfl_xor(v, 32, 64);
      o2[t2][j] = v;
    }
  if (g == 0) {
    #pragma unroll
    for (int t2 = 0; t2 < 2; ++t2) {
      int w = wq*32 + t2*16 + cL;
      float* dst = out + ((size_t)bid*128 + w)*10;
      float tot[10];
      #pragma unroll
      for (int j = 0; j < 10; ++j) tot[j] = o2[t2][j] + fc2_b[j];
      #pragma unroll
      for (int k = 0; k < 5; ++k) dst[k] = tot[2*k];
      #pragma unroll
      for (int k = 0; k < 5; ++k) {
        float sv = tot[2*k+1];
        float sp = fmaxf(sv, 0.f) + log1pf(expf(-fabsf(sv)));
        dst[5 + k] = sp + 1e-4f;
      }
    }
  }
}

extern "C" void kernel_launch(void* const* d_in, const int* in_sizes, int n_in,
                              void* d_out, int out_size, void* d_ws, size_t ws_size,
                              hipStream_t stream) {
  const float* frames = (const float*)d_in[0];
  const float* times  = (const float*)d_in[1];
  const float* lift_w = (const float*)d_in[2];
  const float* lift_b = (const float*)d_in[3];
  const float* spec_w = (const float*)d_in[4];
  const float* skip_w = (const float*)d_in[5];
  const float* skip_b = (const float*)d_in[6];
  const float* agg_w  = (const float*)d_in[7];
  const float* agg_b  = (const float*)d_in[8];
  const float* fc1_w  = (const float*)d_in[9];
  const float* fc1_b  = (const float*)d_in[10];
  const float* fc2_w  = (const float*)d_in[11];
  const float* fc2_b  = (const float*)d_in[12];
  float* out = (float*)d_out;
  char* ws = (char*)d_ws;

  size_t off = 0;
  u16*      xT  = (u16*)(ws + off);      off += (size_t)10240*8192*2;       // 167,772,160
  u16*      xw16= (u16*)(ws + off);      off += (size_t)655360*16*2;        // 20,971,520
  float2*   xf  = (float2*)(ws + off);   off += (size_t)8*1024*64*8;        // 4,194,304
  float2*   yf  = (float2*)(ws + off);   off += (size_t)8*1024*64*8;        // 4,194,304
  unsigned* zh16= (unsigned*)(ws + off); off += (size_t)10240*512*4;        // 20,971,520
  float*    xa  = (float*)(ws + off);    off += (size_t)8*64*128*128*4;     // 33,554,432
  u16*      swf = (u16*)(ws + off);      off += (size_t)32768*2;            // 65,536
  u16*      awf = (u16*)(ws + off);      off += (size_t)81920*2;            // 163,840
  u16*      Tt  = (u16*)(ws + off);      off += (size_t)8192*2;             // 16,384
  float2*   twf = (float2*)(ws + off);   off += (size_t)1024*8;             // 8,192
  u16*      Ef  = (u16*)(ws + off);      off += (size_t)4096*2;             // 8,192
  u16*      f1f = (u16*)(ws + off);      off += (size_t)24576*2;            // 49,152

  k_prep2<<<588, 256, 0, stream>>>(skip_w, agg_w, fc1_w, fc1_b,
                                   swf, awf, Tt, twf, Ef, f1f);
  k_lift_fwdW<<<10240, 128, 0, stream>>>(frames, times, lift_w, lift_b, twf, xT, xw16);

  for (int l = 0; l < 4; ++l) {
    k_fwdHT<<<512, 256, 0, stream>>>((const unsigned*)xw16, xf);
    k_mix<<<256, 256, 0, stream>>>(xf, spec_w + (size_t)l*4*64*64*256*2, yf);
    k_invTH<<<512, 256, 0, stream>>>(yf, zh16);
    k_invW_mfma<<<10240, 256, 0, stream>>>(xT, zh16, swf + (size_t)l*8192, Tt, Ef,
                                           skip_b + l*64, xT, xw16, (l < 3) ? 1 : 0);
  }
  k_agg_mfma<<<1024, 256, 0, stream>>>(xT, awf, agg_b, xa);
  k_head_mfma<<<1024, 256, 0, stream>>>(xa, f1f, fc2_w, fc2_b, out);
}

// Round 21
// 913.496 us; speedup vs baseline: 1.3677x; 1.0258x over previous
//
#include <hip/hip_runtime.h>
#include <math.h>

// FNO3d forward. B=8,T=10,H=128,W=128, C=64, NL=4, modes kt8 kh16 kw8.
// x stored FP16, layout xT[(b*10+t)*128+h][w][ci].
// Round 21: layer-0 fwdW DFT in k_lift_fwdW MFMA-ized (same Ef fragments as
// invW's do_dft epilogue; replaces 128-iter serial scalar-LDS loop).
// invW keeps (256,5). Everything else = r18/r20 best structure.

#define TWO_PI 6.2831853071795864769f
#define ORTHO_SC 2.4705294220065465e-3f  // 1/sqrt(10*128*128)

typedef unsigned short u16;
typedef _Float16 f16;
typedef __attribute__((ext_vector_type(8))) _Float16 f16x8;
typedef __attribute__((ext_vector_type(4))) float f32x4;

#define MFMAH(acc, a, b) acc = __builtin_amdgcn_mfma_f32_16x16x32_f16(a, b, acc, 0, 0, 0)

__device__ __forceinline__ u16 f16b(float v) {
  f16 h = (f16)v;
  return __builtin_bit_cast(u16, h);
}
__device__ __forceinline__ float f16lo(float v) {  // v - fp16(v)
  f16 h = (f16)v;
  return v - (float)h;
}
__device__ __forceinline__ float f16f(u16 b) {
  return (float)__builtin_bit_cast(f16, b);
}
// tanh-approx GELU via exp2 (~9 VALU ops)
__device__ __forceinline__ float gelu_fast(float x) {
  float u = 0.7978845608f * (x + 0.044715f * x * x * x);
  float a = fminf(u * 2.885390082f, 30.0f);
  float e = __builtin_exp2f(a);
  return x * e * __builtin_amdgcn_rcpf(e + 1.0f);
}

// ---------------- prep: A-fragments (split fp16) + twiddle tables ----------------
// swf: [layer4][strip4][kb2][hl2][lane64][8]
// awf: [strip4][t10][kc2][hl2][lane64][8]
// Tt : [hl2][w128][kk32]
// Ef : [hl2][kc4][lane64][8]
// f1f: [strip8][kc3][hl2][lane64][8]  (head fc1^T; k=66 row = fc1_b)
__global__ __launch_bounds__(256) void k_prep2(const float* __restrict__ skip_w,
                                               const float* __restrict__ agg_w,
                                               const float* __restrict__ fc1_w,
                                               const float* __restrict__ fc1_b,
                                               u16* __restrict__ swf,
                                               u16* __restrict__ awf,
                                               u16* __restrict__ Tt,
                                               u16* __restrict__ Ef,
                                               u16* __restrict__ f1f) {
  int e = blockIdx.x*256 + threadIdx.x;
  if (e < 32768) {
    int j = e & 7, lane = (e >> 3) & 63, half = (e >> 9) & 1, ks = (e >> 10) & 1;
    int strip = (e >> 11) & 3, layer = e >> 13;
    int co = strip*16 + (lane & 15);
    int ci = ks*32 + (lane >> 4)*8 + j;
    float v = skip_w[((size_t)(layer*64) + co)*64 + ci];
    swf[e] = half ? f16b(f16lo(v)) : f16b(v);
  } else if (e < 114688) {
    int ee = e - 32768;
    int j = ee & 7, lane = (ee >> 3) & 63;
    int v9 = ee >> 9;
    int half = v9 & 1; v9 >>= 1;
    int ks = v9 & 1; v9 >>= 1;
    int t = v9 % 10, strip = v9 / 10;
    int co = strip*16 + (lane & 15);
    int ci = ks*32 + (lane >> 4)*8 + j;
    float v = agg_w[((size_t)co*64 + ci)*10 + t];
    awf[ee] = half ? f16b(f16lo(v)) : f16b(v);
  } else if (e < 122880) {
    int ee = e - 114688;
    int half = ee >> 12, r = ee & 4095, w = r >> 5, kk = r & 31;
    int m = kk >> 1;
    float val;
    if (kk >= 16) val = 0.f;
    else if (kk == 0) val = 1.f;
    else if (kk == 1) val = 0.f;
    else {
      float th = TWO_PI * (float)m * (float)w / 128.0f;
      val = (kk & 1) ? (-2.f*sinf(th)) : (2.f*cosf(th));
    }
    Tt[ee] = half ? f16b(f16lo(val)) : f16b(val);
  } else if (e < 124928) {
    int ee = e - 122880;
    int j = ee & 7, lane = (ee >> 3) & 63, kc = ee >> 9;
    int n = lane & 15, g = lane >> 4;
    int w = kc*32 + g*8 + j;
    int k = n >> 1;
    float th = TWO_PI * (float)k * (float)w / 128.0f;
    float val = (n & 1) ? (-sinf(th)) : cosf(th);
    Ef[ee] = f16b(val);
    Ef[2048 + ee] = f16b(f16lo(val));
  } else if (e < 149504) {
    int ee = e - 124928;
    int j = ee & 7, lane = (ee >> 3) & 63, hl = (ee >> 9) & 1;
    int rest = ee >> 10;         // 0..23
    int kc = rest % 3, strip = rest / 3;
    int o = strip*16 + (lane & 15);
    int k = kc*32 + (lane >> 4)*8 + j;
    float v;
    if (k < 66) v = fc1_w[(size_t)k*128 + o];
    else if (k == 66) v = fc1_b[o];
    else v = 0.f;
    f1f[ee] = hl ? f16b(f16lo(v)) : f16b(v);
  }
}

// ---------------- fused lift + layer-0 forward-W DFT (MFMA, fp16 xw) ----------------
// 128 threads = 2 waves. Phase 1: lift, pack fp16 to xT + LDS xs[ci][w].
// Phase 2: DFT as MFMA (A = xs rows, B = Ef split twiddles) — same math as
// invW's do_dft epilogue.
__global__ __launch_bounds__(128) void k_lift_fwdW(const float* __restrict__ frames,
                                                   const float* __restrict__ times,
                                                   const float* __restrict__ lift_w,
                                                   const float* __restrict__ lift_b,
                                                   const u16* __restrict__ Ef,
                                                   u16* __restrict__ xT,
                                                   u16* __restrict__ xw16) {
  __shared__ __align__(16) u16 xs[64][136];
  __shared__ float fr[128];
  __shared__ float lw0[64], lw1a[64];
  int bth = blockIdx.x;
  int h = bth & 127; int bt = bth >> 7; int t = bt % 10, b = bt / 10;
  int tid = threadIdx.x;
  float tv = times[b*10 + t];
  fr[tid] = frames[((size_t)(b*10 + t)*128 + h)*128 + tid];
  if (tid < 64) { lw0[tid] = lift_w[2*tid]; lw1a[tid] = lift_w[2*tid+1]*tv + lift_b[tid]; }
  __syncthreads();
  {
    int w = tid;
    float f = fr[w];
    unsigned pk[32];
    #pragma unroll
    for (int q = 0; q < 32; ++q) {
      float v0 = f*lw0[2*q] + lw1a[2*q];
      float v1 = f*lw0[2*q+1] + lw1a[2*q+1];
      u16 h0 = f16b(v0), h1 = f16b(v1);
      xs[2*q][w] = h0; xs[2*q+1][w] = h1;
      pk[q] = (unsigned)h0 | ((unsigned)h1 << 16);
    }
    uint4* d4 = (uint4*)(xT + (size_t)bth*8192 + w*64);
    #pragma unroll
    for (int q = 0; q < 8; ++q)
      d4[q] = make_uint4(pk[4*q], pk[4*q+1], pk[4*q+2], pk[4*q+3]);
  }
  __syncthreads();
  {
    int lane = tid & 63, wv = tid >> 6, cL = lane & 15, g = lane >> 4;
    int s0 = wv*2, s1 = wv*2 + 1;
    f32x4 acc0 = (f32x4){0.f,0.f,0.f,0.f};
    f32x4 acc1 = (f32x4){0.f,0.f,0.f,0.f};
    #pragma unroll
    for (int kc = 0; kc < 4; ++kc) {
      f16x8 eh = *(const f16x8*)(Ef + (kc*64 + lane)*8);
      f16x8 el = *(const f16x8*)(Ef + 2048 + (kc*64 + lane)*8);
      f16x8 a0 = *(const f16x8*)(&xs[s0*16 + cL][kc*32 + g*8]);
      f16x8 a1 = *(const f16x8*)(&xs[s1*16 + cL][kc*32 + g*8]);
      MFMAH(acc0, a0, eh);
      MFMAH(acc0, a0, el);
      MFMAH(acc1, a1, eh);
      MFMAH(acc1, a1, el);
    }
    #pragma unroll
    for (int r = 0; r < 4; ++r) {
      int ci0 = s0*16 + g*4 + r;
      size_t row0 = ((size_t)(b*64 + ci0)*10 + t)*128 + h;
      xw16[row0*16 + cL] = f16b(acc0[r]);
      int ci1 = s1*16 + g*4 + r;
      size_t row1 = ((size_t)(b*64 + ci1)*10 + t)*128 + h;
      xw16[row1*16 + cL] = f16b(acc1[r]);
    }
  }
}

// ---------------- fused forward H+T stages (fp16 xw input) ----------------
__global__ __launch_bounds__(256) void k_fwdHT(const unsigned* __restrict__ xw32,
                                               float2* __restrict__ xf) {
  __shared__ unsigned tile[2][1024];
  __shared__ float2 parts1[1024];
  __shared__ float2 tw128[128];
  int bc = blockIdx.x;
  int b = bc >> 6, c = bc & 63;
  int tid = threadIdx.x;
  if (tid < 128) {
    float s, co; sincosf(TWO_PI * (float)tid / 128.0f, &s, &co);
    tw128[tid] = make_float2(co, -s);
  }
  int tpar = tid >> 7, j = tid & 127;
  int khi = j >> 3, kwi = j & 7;
  int kh = (khi < 8) ? khi : (112 + khi);
  float accr[8], acci[8];
  #pragma unroll
  for (int k = 0; k < 8; ++k) { accr[k] = 0.f; acci[k] = 0.f; }
  for (int tt = 0; tt < 5; ++tt) {
    __syncthreads();
    for (int u = tid; u < 2048; u += 256) {
      int tg = u >> 10, idx = u & 1023;
      tile[tg][idx] = xw32[((size_t)bc*10 + tg*5 + tt)*1024 + idx];
    }
    __syncthreads();
    float xr = 0.f, xi = 0.f;
    for (int h = 0; h < 128; ++h) {
      unsigned uv = tile[tpar][h*8 + kwi];
      float vx = f16f((u16)uv);
      float vy = f16f((u16)(uv >> 16));
      float2 tw = tw128[(h*kh) & 127];
      xr += vx*tw.x - vy*tw.y;
      xi += vx*tw.y + vy*tw.x;
    }
    int t = tpar*5 + tt;
    float sb, cb; sincosf(TWO_PI * (float)t / 10.0f, &sb, &cb);
    float p_r[10], p_i[10];
    p_r[0] = 1.f; p_i[0] = 0.f; p_r[1] = cb; p_i[1] = -sb;
    #pragma unroll
    for (int k = 2; k < 10; ++k) {
      p_r[k] = p_r[k-1]*p_r[1] - p_i[k-1]*p_i[1];
      p_i[k] = p_r[k-1]*p_i[1] + p_i[k-1]*p_r[1];
    }
    #pragma unroll
    for (int kti = 0; kti < 8; ++kti) {
      int kt = (kti < 4) ? kti : kti + 2;
      accr[kti] += xr*p_r[kt] - xi*p_i[kt];
      acci[kti] += xr*p_i[kt] + xi*p_r[kt];
    }
  }
  __syncthreads();
  if (tpar == 1) {
    #pragma unroll
    for (int kti = 0; kti < 8; ++kti)
      parts1[j*8 + kti] = make_float2(accr[kti], acci[kti]);
  }
  __syncthreads();
  if (tpar == 0) {
    #pragma unroll
    for (int kti = 0; kti < 8; ++kti) {
      float2 bq = parts1[j*8 + kti];
      xf[((size_t)b*1024 + kti*128 + j)*64 + c] =
          make_float2((accr[kti] + bq.x)*ORTHO_SC, (acci[kti] + bq.y)*ORTHO_SC);
    }
  }
}

// ---------------- channel mix (reads spec_w original layout directly) ----------------
__global__ __launch_bounds__(256) void k_mix(const float2* __restrict__ xf,
                                             const float* __restrict__ spec_w_l,
                                             float2* __restrict__ yf) {
  __shared__ float2 xfs[8][4][64];
  int m0 = blockIdx.x * 4;
  for (int i = threadIdx.x; i < 2048; i += 256) {
    int bb = i >> 8, mi = (i >> 6) & 3, ci = i & 63;
    xfs[bb][mi][ci] = xf[((size_t)bb*1024 + m0 + mi)*64 + ci];
  }
  __syncthreads();
  int co = threadIdx.x & 63, mi = threadIdx.x >> 6;
  int m = m0 + mi;
  int kti = m >> 7, khi = (m >> 3) & 15, kwi = m & 7;
  int q = ((kti >= 4) ? 2 : 0) + ((khi >= 8) ? 1 : 0);
  int modeidx = ((kti & 3)*8 + (khi & 7))*8 + kwi;
  const float2* wp = (const float2*)spec_w_l
                     + ((size_t)(q*64)*64 + co)*256 + modeidx;
  float accr[8], acci[8];
  #pragma unroll
  for (int bb = 0; bb < 8; ++bb) { accr[bb] = 0.f; acci[bb] = 0.f; }
  for (int ci = 0; ci < 64; ++ci) {
    float2 wv = wp[(size_t)ci*16384];
    #pragma unroll
    for (int bb = 0; bb < 8; ++bb) {
      float2 xv = xfs[bb][mi][ci];
      accr[bb] += xv.x*wv.x - xv.y*wv.y;
      acci[bb] += xv.x*wv.y + xv.y*wv.x;
    }
  }
  #pragma unroll
  for (int bb = 0; bb < 8; ++bb)
    yf[((size_t)bb*64 + co)*1024 + m] = make_float2(accr[bb], acci[bb]);
}

// ---------------- fused inverse T+H stages (fp16-packed output) ----------------
__global__ __launch_bounds__(256) void k_invTH(const float2* __restrict__ yf,
                                               unsigned* __restrict__ zh16) {
  __shared__ float2 ybuf[1024];
  __shared__ float2 ztb[2][128];
  __shared__ float2 tw128[128];
  int bc = blockIdx.x;
  int b = bc >> 6, c = bc & 63;
  int tid = threadIdx.x;
  for (int u = tid; u < 1024; u += 256) ybuf[u] = yf[(size_t)bc*1024 + u];
  if (tid < 128) {
    float s, co; sincosf(TWO_PI * (float)tid / 128.0f, &s, &co);
    tw128[tid] = make_float2(co, s);
  }
  int tpar = tid >> 7, j = tid & 127;
  __syncthreads();
  for (int tt = 0; tt < 5; ++tt) {
    int t = tt*2 + tpar;
    {
      float sb, cb; sincosf(TWO_PI * (float)t / 10.0f, &sb, &cb);
      float p_r[10], p_i[10];
      p_r[0] = 1.f; p_i[0] = 0.f; p_r[1] = cb; p_i[1] = sb;
      #pragma unroll
      for (int k = 2; k < 10; ++k) {
        p_r[k] = p_r[k-1]*p_r[1] - p_i[k-1]*p_i[1];
        p_i[k] = p_r[k-1]*p_i[1] + p_i[k-1]*p_r[1];
      }
      float zr = 0.f, zi = 0.f;
      #pragma unroll
      for (int kti = 0; kti < 8; ++kti) {
        int kt = (kti < 4) ? kti : kti + 2;
        float2 v = ybuf[kti*128 + j];
        zr += v.x*p_r[kt] - v.y*p_i[kt];
        zi += v.x*p_i[kt] + v.y*p_r[kt];
      }
      ztb[tpar][j] = make_float2(zr*ORTHO_SC, zi*ORTHO_SC);
    }
    __syncthreads();
    {
      int h = j;
      float ar[8], ai[8];
      #pragma unroll
      for (int kw = 0; kw < 8; ++kw) { ar[kw] = 0.f; ai[kw] = 0.f; }
      #pragma unroll
      for (int khi = 0; khi < 16; ++khi) {
        int kh = (khi < 8) ? khi : (112 + khi);
        float2 tw = tw128[(h*kh) & 127];
        #pragma unroll
        for (int kw = 0; kw < 8; ++kw) {
          float2 v = ztb[tpar][khi*8 + kw];
          ar[kw] += v.x*tw.x - v.y*tw.y;
          ai[kw] += v.x*tw.y + v.y*tw.x;
        }
      }
      unsigned* dst = zh16 + (((size_t)(b*10 + t)*128 + h)*64 + c)*8;
      #pragma unroll
      for (int kw = 0; kw < 8; ++kw)
        dst[kw] = (unsigned)f16b(ar[kw]) | ((unsigned)f16b(ai[kw]) << 16);
    }
    __syncthreads();
  }
}

// ---------------- fused inverse-W + skip + GELU (+ next-layer fwdW DFT) ----------------
// T-block uses hi-half twiddles only; Th loaded at use (48 VGPR); (256,5).
__global__ __launch_bounds__(256, 5) void k_invW_mfma(const u16* __restrict__ xTin,
                                                      const unsigned* __restrict__ zh16,
                                                      const u16* __restrict__ swf_l,
                                                      const u16* __restrict__ Tt,
                                                      const u16* __restrict__ Ef,
                                                      const float* __restrict__ skb,
                                                      u16* __restrict__ xTo,
                                                      u16* __restrict__ xw16,
                                                      int do_dft) {
  __shared__ __align__(16) char smem[20480];
  u16* B = (u16*)smem;              // [128][72]
  u16* zAh = (u16*)(smem + 18432);  // [64][16]
  int tid = threadIdx.x;
  int bth = blockIdx.x;
  int lane = tid & 63;
  int wq = tid >> 6;
  int cL = lane & 15;
  int g = lane >> 4;

  {
    const uint4* xsrc = (const uint4*)(xTin + (size_t)bth*8192);
    for (int u = tid; u < 1024; u += 256) {
      int w = u >> 3, c = u & 7;
      ((uint4*)(B + w*72))[c] = xsrc[u];
    }
  }
  {
    const unsigned* zsrc = zh16 + (size_t)bth*512;
    for (int u = tid; u < 512; u += 256) {
      int co = u >> 3, m = u & 7;
      *(unsigned*)(zAh + co*16 + 2*m) = zsrc[u];
    }
  }
  __syncthreads();

  f32x4 acc[4][2];
  #pragma unroll
  for (int s = 0; s < 4; ++s)
    #pragma unroll
    for (int t2 = 0; t2 < 2; ++t2) acc[s][t2] = (f32x4){0.f,0.f,0.f,0.f};

  #pragma unroll
  for (int kb = 0; kb < 2; ++kb) {
    f16x8 Ah[4], Al[4];
    #pragma unroll
    for (int s = 0; s < 4; ++s) {
      Ah[s] = *(const f16x8*)(swf_l + (size_t)(s*2048 + kb*1024 + lane*8));
      Al[s] = *(const f16x8*)(swf_l + (size_t)(s*2048 + kb*1024 + 512 + lane*8));
    }
    #pragma unroll
    for (int t2 = 0; t2 < 2; ++t2) {
      int wrow = wq*32 + t2*16 + cL;
      f16x8 bh = *(const f16x8*)(B + wrow*72 + kb*32 + g*8);
      #pragma unroll
      for (int s = 0; s < 4; ++s) {
        MFMAH(acc[s][t2], Ah[s], bh);
        MFMAH(acc[s][t2], Al[s], bh);
      }
    }
  }
  {
    f16x8 Azh[4];
    f16x8 zero8 = {0,0,0,0,0,0,0,0};
    #pragma unroll
    for (int s = 0; s < 4; ++s)
      Azh[s] = (g < 2) ? *(const f16x8*)(zAh + (s*16 + cL)*16 + g*8) : zero8;
    #pragma unroll
    for (int t2 = 0; t2 < 2; ++t2) {
      int wrow = wq*32 + t2*16 + cL;
      f16x8 th = *(const f16x8*)(Tt + wrow*32 + g*8);
      #pragma unroll
      for (int s = 0; s < 4; ++s) {
        MFMAH(acc[s][t2], Azh[s], th);
      }
    }
  }

  __syncthreads();
  unsigned* out32 = (unsigned*)smem;           // [32][130] u32 (aliases B)
  #pragma unroll
  for (int s = 0; s < 4; ++s) {
    float4 b4 = *(const float4*)(skb + s*16 + g*4);
    float bb[4] = {b4.x, b4.y, b4.z, b4.w};
    #pragma unroll
    for (int t2 = 0; t2 < 2; ++t2) {
      int w = wq*32 + t2*16 + cL;
      u16 gb[4];
      #pragma unroll
      for (int r = 0; r < 4; ++r) {
        float val = acc[s][t2][r] + bb[r];
        gb[r] = f16b(gelu_fast(val));
      }
      out32[(s*8 + g*2 + 0)*130 + w] = (unsigned)gb[0] | ((unsigned)gb[1] << 16);
      out32[(s*8 + g*2 + 1)*130 + w] = (unsigned)gb[2] | ((unsigned)gb[3] << 16);
    }
  }
  __syncthreads();
  {
    uint4* xdst = (uint4*)(xTo + (size_t)bth*8192);
    for (int u = tid; u < 1024; u += 256) {
      int w = u >> 3, c = u & 7;
      unsigned r0 = out32[(c*4 + 0)*130 + w];
      unsigned r1 = out32[(c*4 + 1)*130 + w];
      unsigned r2 = out32[(c*4 + 2)*130 + w];
      unsigned r3 = out32[(c*4 + 3)*130 + w];
      xdst[u] = make_uint4(r0, r1, r2, r3);
    }
  }
  if (do_dft) {
    f32x4 acc2 = (f32x4){0.f,0.f,0.f,0.f};
    int row = wq*8 + (cL >> 1);
    int sh = (cL & 1) * 16;
    #pragma unroll
    for (int kc = 0; kc < 4; ++kc) {
      const unsigned* p = out32 + row*130 + kc*32 + g*8;
      uint2 d0 = *(const uint2*)(p);
      uint2 d1 = *(const uint2*)(p + 2);
      uint2 d2 = *(const uint2*)(p + 4);
      uint2 d3 = *(const uint2*)(p + 6);
      f16x8 a;
      a[0] = __builtin_bit_cast(f16, (u16)(d0.x >> sh));
      a[1] = __builtin_bit_cast(f16, (u16)(d0.y >> sh));
      a[2] = __builtin_bit_cast(f16, (u16)(d1.x >> sh));
      a[3] = __builtin_bit_cast(f16, (u16)(d1.y >> sh));
      a[4] = __builtin_bit_cast(f16, (u16)(d2.x >> sh));
      a[5] = __builtin_bit_cast(f16, (u16)(d2.y >> sh));
      a[6] = __builtin_bit_cast(f16, (u16)(d3.x >> sh));
      a[7] = __builtin_bit_cast(f16, (u16)(d3.y >> sh));
      f16x8 eh = *(const f16x8*)(Ef + (kc*64 + lane)*8);
      f16x8 el = *(const f16x8*)(Ef + 2048 + (kc*64 + lane)*8);
      MFMAH(acc2, a, eh);
      MFMAH(acc2, a, el);
    }
    int h = bth & 127; int bt = bth >> 7; int t = bt % 10, b = bt / 10;
    #pragma unroll
    for (int r = 0; r < 4; ++r) {
      int co = wq*16 + g*4 + r;
      size_t row2 = ((size_t)(b*64 + co)*10 + t)*128 + h;
      xw16[row2*16 + cL] = f16b(acc2[r]);
    }
  }
}

// ---------------- aggregation (K=640) as fp16 MFMA (exact B, direct stores) ----------------
__global__ __launch_bounds__(256) void k_agg_mfma(const u16* __restrict__ xT,
                                                  const u16* __restrict__ awf,
                                                  const float* __restrict__ agg_b,
                                                  float* __restrict__ xa) {
  __shared__ __align__(16) u16 B[128*72];   // 18432 B
  int tid = threadIdx.x;
  int bid = blockIdx.x;
  int h = bid & 127, b = bid >> 7;
  int lane = tid & 63;
  int wq = tid >> 6;
  int cL = lane & 15;
  int g = lane >> 4;

  f32x4 acc[4][2];
  #pragma unroll
  for (int s = 0; s < 4; ++s)
    #pragma unroll
    for (int t2 = 0; t2 < 2; ++t2) acc[s][t2] = (f32x4){0.f,0.f,0.f,0.f};

  for (int t = 0; t < 10; ++t) {
    __syncthreads();
    {
      const uint4* xsrc = (const uint4*)(xT + ((size_t)(b*10 + t)*128 + h)*8192);
      for (int u = tid; u < 1024; u += 256) {
        int w = u >> 3, c = u & 7;
        ((uint4*)(B + w*72))[c] = xsrc[u];
      }
    }
    __syncthreads();
    #pragma unroll
    for (int kc = 0; kc < 2; ++kc) {
      f16x8 Ah[4], Al[4];
      #pragma unroll
      for (int s = 0; s < 4; ++s) {
        const u16* af = awf + (size_t)((s*10 + t)*4 + kc*2)*512;
        Ah[s] = *(const f16x8*)(af + lane*8);
        Al[s] = *(const f16x8*)(af + 512 + lane*8);
      }
      #pragma unroll
      for (int t2 = 0; t2 < 2; ++t2) {
        int wrow = wq*32 + t2*16 + cL;
        f16x8 bh = *(const f16x8*)(B + wrow*72 + kc*32 + g*8);
        #pragma unroll
        for (int s = 0; s < 4; ++s) {
          MFMAH(acc[s][t2], Ah[s], bh);
          MFMAH(acc[s][t2], Al[s], bh);
        }
      }
    }
  }

  #pragma unroll
  for (int s = 0; s < 4; ++s) {
    float4 b4 = *(const float4*)(agg_b + s*16 + g*4);
    float bb[4] = {b4.x, b4.y, b4.z, b4.w};
    #pragma unroll
    for (int t2 = 0; t2 < 2; ++t2) {
      int w = wq*32 + t2*16 + cL;
      #pragma unroll
      for (int r = 0; r < 4; ++r) {
        int co = s*16 + g*4 + r;
        xa[((size_t)(b*64 + co)*128 + h)*128 + w] = acc[s][t2][r] + bb[r];
      }
    }
  }
}

// ---------------- head as split-fp16 MFMA: M=128 o, N=128 w, K=96 ----------------
__global__ __launch_bounds__(256) void k_head_mfma(const float* __restrict__ xa,
                                                   const u16* __restrict__ f1f,
                                                   const float* __restrict__ fc2_w,
                                                   const float* __restrict__ fc2_b,
                                                   float* __restrict__ out) {
  __shared__ __align__(16) u16 B[128*128];   // 32768 B
  __shared__ float w2s[1280];
  int tid = threadIdx.x;
  int bid = blockIdx.x;
  int h = bid & 127, b = bid >> 7;
  for (int i = tid; i < 1280; i += 256) w2s[i] = fc2_w[i];
  for (int u = tid; u < 2048; u += 256) {
    int co = u >> 5, w4 = u & 31;
    float4 v = *(const float4*)(xa + ((size_t)(b*64 + co)*128 + h)*128 + w4*4);
    float vv[4] = {v.x, v.y, v.z, v.w};
    int kg = co >> 3, kj = co & 7;
    #pragma unroll
    for (int jj = 0; jj < 4; ++jj) {
      int w = w4*4 + jj;
      B[w*128 + ((kg ^ (w & 7)) << 3) + kj] = f16b(vv[jj]);
    }
  }
  for (int u = tid; u < 512; u += 256) {
    int w = u & 127, kgo = u >> 7;
    int kg = 8 + kgo;
    u16* dst = &B[w*128 + ((kg ^ (w & 7)) << 3)];
    if (kgo == 0) {
      float gx = -1.f + 2.f*(float)w/127.f;
      float gy = -1.f + 2.f*(float)h/127.f;
      dst[0] = f16b(gx); dst[1] = f16b(gy); dst[2] = f16b(1.f);
      dst[3] = 0; dst[4] = 0; dst[5] = 0; dst[6] = 0; dst[7] = 0;
    } else {
      #pragma unroll
      for (int q = 0; q < 8; ++q) dst[q] = 0;
    }
  }
  __syncthreads();

  int lane = tid & 63, wq = tid >> 6, cL = lane & 15, g = lane >> 4;
  f32x4 acc[8][2];
  #pragma unroll
  for (int s = 0; s < 8; ++s)
    #pragma unroll
    for (int t2 = 0; t2 < 2; ++t2) acc[s][t2] = (f32x4){0.f,0.f,0.f,0.f};

  #pragma unroll
  for (int kc = 0; kc < 3; ++kc) {
    f16x8 bfr[2];
    #pragma unroll
    for (int t2 = 0; t2 < 2; ++t2) {
      int wrow = wq*32 + t2*16 + cL;
      int kg = kc*4 + g;
      bfr[t2] = *(const f16x8*)(&B[wrow*128 + ((kg ^ (wrow & 7)) << 3)]);
    }
    #pragma unroll
    for (int s = 0; s < 8; ++s) {
      f16x8 Ah = *(const f16x8*)(f1f + (size_t)(((s*3 + kc)*2 + 0)*64 + lane)*8);
      f16x8 Al = *(const f16x8*)(f1f + (size_t)(((s*3 + kc)*2 + 1)*64 + lane)*8);
      #pragma unroll
      for (int t2 = 0; t2 < 2; ++t2) {
        MFMAH(acc[s][t2], Ah, bfr[t2]);
        MFMAH(acc[s][t2], Al, bfr[t2]);
      }
    }
  }

  float o2[2][10];
  #pragma unroll
  for (int t2 = 0; t2 < 2; ++t2)
    #pragma unroll
    for (int j = 0; j < 10; ++j) o2[t2][j] = 0.f;
  #pragma unroll
  for (int s = 0; s < 8; ++s) {
    #pragma unroll
    for (int t2 = 0; t2 < 2; ++t2) {
      #pragma unroll
      for (int r = 0; r < 4; ++r) {
        int o = s*16 + g*4 + r;
        float gl = gelu_fast(acc[s][t2][r]);
        #pragma unroll
        for (int j = 0; j < 10; ++j) o2[t2][j] += gl * w2s[o*10 + j];
      }
    }
  }
  #pragma unroll
  for (int t2 = 0; t2 < 2; ++t2)
    #pragma unroll
    for (int j = 0; j < 10; ++j) {
      float v = o2[t2][j];
      v += __shfl_xor(v, 16, 64);
      v += __shfl_xor(v, 32, 64);
      o2[t2][j] = v;
    }
  if (g == 0) {
    #pragma unroll
    for (int t2 = 0; t2 < 2; ++t2) {
      int w = wq*32 + t2*16 + cL;
      float* dst = out + ((size_t)bid*128 + w)*10;
      float tot[10];
      #pragma unroll
      for (int j = 0; j < 10; ++j) tot[j] = o2[t2][j] + fc2_b[j];
      #pragma unroll
      for (int k = 0; k < 5; ++k) dst[k] = tot[2*k];
      #pragma unroll
      for (int k = 0; k < 5; ++k) {
        float sv = tot[2*k+1];
        float sp = fmaxf(sv, 0.f) + log1pf(expf(-fabsf(sv)));
        dst[5 + k] = sp + 1e-4f;
      }
    }
  }
}

extern "C" void kernel_launch(void* const* d_in, const int* in_sizes, int n_in,
                              void* d_out, int out_size, void* d_ws, size_t ws_size,
                              hipStream_t stream) {
  const float* frames = (const float*)d_in[0];
  const float* times  = (const float*)d_in[1];
  const float* lift_w = (const float*)d_in[2];
  const float* lift_b = (const float*)d_in[3];
  const float* spec_w = (const float*)d_in[4];
  const float* skip_w = (const float*)d_in[5];
  const float* skip_b = (const float*)d_in[6];
  const float* agg_w  = (const float*)d_in[7];
  const float* agg_b  = (const float*)d_in[8];
  const float* fc1_w  = (const float*)d_in[9];
  const float* fc1_b  = (const float*)d_in[10];
  const float* fc2_w  = (const float*)d_in[11];
  const float* fc2_b  = (const float*)d_in[12];
  float* out = (float*)d_out;
  char* ws = (char*)d_ws;

  size_t off = 0;
  u16*      xT  = (u16*)(ws + off);      off += (size_t)10240*8192*2;       // 167,772,160
  u16*      xw16= (u16*)(ws + off);      off += (size_t)655360*16*2;        // 20,971,520
  float2*   xf  = (float2*)(ws + off);   off += (size_t)8*1024*64*8;        // 4,194,304
  float2*   yf  = (float2*)(ws + off);   off += (size_t)8*1024*64*8;        // 4,194,304
  unsigned* zh16= (unsigned*)(ws + off); off += (size_t)10240*512*4;        // 20,971,520
  float*    xa  = (float*)(ws + off);    off += (size_t)8*64*128*128*4;     // 33,554,432
  u16*      swf = (u16*)(ws + off);      off += (size_t)32768*2;            // 65,536
  u16*      awf = (u16*)(ws + off);      off += (size_t)81920*2;            // 163,840
  u16*      Tt  = (u16*)(ws + off);      off += (size_t)8192*2;             // 16,384
  u16*      Ef  = (u16*)(ws + off);      off += (size_t)4096*2;             // 8,192
  u16*      f1f = (u16*)(ws + off);      off += (size_t)24576*2;            // 49,152

  k_prep2<<<584, 256, 0, stream>>>(skip_w, agg_w, fc1_w, fc1_b,
                                   swf, awf, Tt, Ef, f1f);
  k_lift_fwdW<<<10240, 128, 0, stream>>>(frames, times, lift_w, lift_b, Ef, xT, xw16);

  for (int l = 0; l < 4; ++l) {
    k_fwdHT<<<512, 256, 0, stream>>>((const unsigned*)xw16, xf);
    k_mix<<<256, 256, 0, stream>>>(xf, spec_w + (size_t)l*4*64*64*256*2, yf);
    k_invTH<<<512, 256, 0, stream>>>(yf, zh16);
    k_invW_mfma<<<10240, 256, 0, stream>>>(xT, zh16, swf + (size_t)l*8192, Tt, Ef,
                                           skip_b + l*64, xT, xw16, (l < 3) ? 1 : 0);
  }
  k_agg_mfma<<<1024, 256, 0, stream>>>(xT, awf, agg_b, xa);
  k_head_mfma<<<1024, 256, 0, stream>>>(xa, f1f, fc2_w, fc2_b, out);
}

// Round 22
// 912.841 us; speedup vs baseline: 1.3687x; 1.0007x over previous
//
#include <hip/hip_runtime.h>
#include <math.h>

// FNO3d forward. B=8,T=10,H=128,W=128, C=64, NL=4, modes kt8 kh16 kw8.
// x stored FP16, layout xT[(b*10+t)*128+h][w][ci].
// Round 22: r21 + double-buffered LDS staging in k_agg_mfma (one barrier per
// t-iteration; stage t+1 overlaps MFMA of t). Everything else identical.

#define TWO_PI 6.2831853071795864769f
#define ORTHO_SC 2.4705294220065465e-3f  // 1/sqrt(10*128*128)

typedef unsigned short u16;
typedef _Float16 f16;
typedef __attribute__((ext_vector_type(8))) _Float16 f16x8;
typedef __attribute__((ext_vector_type(4))) float f32x4;

#define MFMAH(acc, a, b) acc = __builtin_amdgcn_mfma_f32_16x16x32_f16(a, b, acc, 0, 0, 0)

__device__ __forceinline__ u16 f16b(float v) {
  f16 h = (f16)v;
  return __builtin_bit_cast(u16, h);
}
__device__ __forceinline__ float f16lo(float v) {  // v - fp16(v)
  f16 h = (f16)v;
  return v - (float)h;
}
__device__ __forceinline__ float f16f(u16 b) {
  return (float)__builtin_bit_cast(f16, b);
}
// tanh-approx GELU via exp2 (~9 VALU ops)
__device__ __forceinline__ float gelu_fast(float x) {
  float u = 0.7978845608f * (x + 0.044715f * x * x * x);
  float a = fminf(u * 2.885390082f, 30.0f);
  float e = __builtin_exp2f(a);
  return x * e * __builtin_amdgcn_rcpf(e + 1.0f);
}

// ---------------- prep: A-fragments (split fp16) + twiddle tables ----------------
// swf: [layer4][strip4][kb2][hl2][lane64][8]
// awf: [strip4][t10][kc2][hl2][lane64][8]
// Tt : [hl2][w128][kk32]
// Ef : [hl2][kc4][lane64][8]
// f1f: [strip8][kc3][hl2][lane64][8]  (head fc1^T; k=66 row = fc1_b)
__global__ __launch_bounds__(256) void k_prep2(const float* __restrict__ skip_w,
                                               const float* __restrict__ agg_w,
                                               const float* __restrict__ fc1_w,
                                               const float* __restrict__ fc1_b,
                                               u16* __restrict__ swf,
                                               u16* __restrict__ awf,
                                               u16* __restrict__ Tt,
                                               u16* __restrict__ Ef,
                                               u16* __restrict__ f1f) {
  int e = blockIdx.x*256 + threadIdx.x;
  if (e < 32768) {
    int j = e & 7, lane = (e >> 3) & 63, half = (e >> 9) & 1, ks = (e >> 10) & 1;
    int strip = (e >> 11) & 3, layer = e >> 13;
    int co = strip*16 + (lane & 15);
    int ci = ks*32 + (lane >> 4)*8 + j;
    float v = skip_w[((size_t)(layer*64) + co)*64 + ci];
    swf[e] = half ? f16b(f16lo(v)) : f16b(v);
  } else if (e < 114688) {
    int ee = e - 32768;
    int j = ee & 7, lane = (ee >> 3) & 63;
    int v9 = ee >> 9;
    int half = v9 & 1; v9 >>= 1;
    int ks = v9 & 1; v9 >>= 1;
    int t = v9 % 10, strip = v9 / 10;
    int co = strip*16 + (lane & 15);
    int ci = ks*32 + (lane >> 4)*8 + j;
    float v = agg_w[((size_t)co*64 + ci)*10 + t];
    awf[ee] = half ? f16b(f16lo(v)) : f16b(v);
  } else if (e < 122880) {
    int ee = e - 114688;
    int half = ee >> 12, r = ee & 4095, w = r >> 5, kk = r & 31;
    int m = kk >> 1;
    float val;
    if (kk >= 16) val = 0.f;
    else if (kk == 0) val = 1.f;
    else if (kk == 1) val = 0.f;
    else {
      float th = TWO_PI * (float)m * (float)w / 128.0f;
      val = (kk & 1) ? (-2.f*sinf(th)) : (2.f*cosf(th));
    }
    Tt[ee] = half ? f16b(f16lo(val)) : f16b(val);
  } else if (e < 124928) {
    int ee = e - 122880;
    int j = ee & 7, lane = (ee >> 3) & 63, kc = ee >> 9;
    int n = lane & 15, g = lane >> 4;
    int w = kc*32 + g*8 + j;
    int k = n >> 1;
    float th = TWO_PI * (float)k * (float)w / 128.0f;
    float val = (n & 1) ? (-sinf(th)) : cosf(th);
    Ef[ee] = f16b(val);
    Ef[2048 + ee] = f16b(f16lo(val));
  } else if (e < 149504) {
    int ee = e - 124928;
    int j = ee & 7, lane = (ee >> 3) & 63, hl = (ee >> 9) & 1;
    int rest = ee >> 10;         // 0..23
    int kc = rest % 3, strip = rest / 3;
    int o = strip*16 + (lane & 15);
    int k = kc*32 + (lane >> 4)*8 + j;
    float v;
    if (k < 66) v = fc1_w[(size_t)k*128 + o];
    else if (k == 66) v = fc1_b[o];
    else v = 0.f;
    f1f[ee] = hl ? f16b(f16lo(v)) : f16b(v);
  }
}

// ---------------- fused lift + layer-0 forward-W DFT (MFMA, fp16 xw) ----------------
__global__ __launch_bounds__(128) void k_lift_fwdW(const float* __restrict__ frames,
                                                   const float* __restrict__ times,
                                                   const float* __restrict__ lift_w,
                                                   const float* __restrict__ lift_b,
                                                   const u16* __restrict__ Ef,
                                                   u16* __restrict__ xT,
                                                   u16* __restrict__ xw16) {
  __shared__ __align__(16) u16 xs[64][136];
  __shared__ float fr[128];
  __shared__ float lw0[64], lw1a[64];
  int bth = blockIdx.x;
  int h = bth & 127; int bt = bth >> 7; int t = bt % 10, b = bt / 10;
  int tid = threadIdx.x;
  float tv = times[b*10 + t];
  fr[tid] = frames[((size_t)(b*10 + t)*128 + h)*128 + tid];
  if (tid < 64) { lw0[tid] = lift_w[2*tid]; lw1a[tid] = lift_w[2*tid+1]*tv + lift_b[tid]; }
  __syncthreads();
  {
    int w = tid;
    float f = fr[w];
    unsigned pk[32];
    #pragma unroll
    for (int q = 0; q < 32; ++q) {
      float v0 = f*lw0[2*q] + lw1a[2*q];
      float v1 = f*lw0[2*q+1] + lw1a[2*q+1];
      u16 h0 = f16b(v0), h1 = f16b(v1);
      xs[2*q][w] = h0; xs[2*q+1][w] = h1;
      pk[q] = (unsigned)h0 | ((unsigned)h1 << 16);
    }
    uint4* d4 = (uint4*)(xT + (size_t)bth*8192 + w*64);
    #pragma unroll
    for (int q = 0; q < 8; ++q)
      d4[q] = make_uint4(pk[4*q], pk[4*q+1], pk[4*q+2], pk[4*q+3]);
  }
  __syncthreads();
  {
    int lane = tid & 63, wv = tid >> 6, cL = lane & 15, g = lane >> 4;
    int s0 = wv*2, s1 = wv*2 + 1;
    f32x4 acc0 = (f32x4){0.f,0.f,0.f,0.f};
    f32x4 acc1 = (f32x4){0.f,0.f,0.f,0.f};
    #pragma unroll
    for (int kc = 0; kc < 4; ++kc) {
      f16x8 eh = *(const f16x8*)(Ef + (kc*64 + lane)*8);
      f16x8 el = *(const f16x8*)(Ef + 2048 + (kc*64 + lane)*8);
      f16x8 a0 = *(const f16x8*)(&xs[s0*16 + cL][kc*32 + g*8]);
      f16x8 a1 = *(const f16x8*)(&xs[s1*16 + cL][kc*32 + g*8]);
      MFMAH(acc0, a0, eh);
      MFMAH(acc0, a0, el);
      MFMAH(acc1, a1, eh);
      MFMAH(acc1, a1, el);
    }
    #pragma unroll
    for (int r = 0; r < 4; ++r) {
      int ci0 = s0*16 + g*4 + r;
      size_t row0 = ((size_t)(b*64 + ci0)*10 + t)*128 + h;
      xw16[row0*16 + cL] = f16b(acc0[r]);
      int ci1 = s1*16 + g*4 + r;
      size_t row1 = ((size_t)(b*64 + ci1)*10 + t)*128 + h;
      xw16[row1*16 + cL] = f16b(acc1[r]);
    }
  }
}

// ---------------- fused forward H+T stages (fp16 xw input) ----------------
__global__ __launch_bounds__(256) void k_fwdHT(const unsigned* __restrict__ xw32,
                                               float2* __restrict__ xf) {
  __shared__ unsigned tile[2][1024];
  __shared__ float2 parts1[1024];
  __shared__ float2 tw128[128];
  int bc = blockIdx.x;
  int b = bc >> 6, c = bc & 63;
  int tid = threadIdx.x;
  if (tid < 128) {
    float s, co; sincosf(TWO_PI * (float)tid / 128.0f, &s, &co);
    tw128[tid] = make_float2(co, -s);
  }
  int tpar = tid >> 7, j = tid & 127;
  int khi = j >> 3, kwi = j & 7;
  int kh = (khi < 8) ? khi : (112 + khi);
  float accr[8], acci[8];
  #pragma unroll
  for (int k = 0; k < 8; ++k) { accr[k] = 0.f; acci[k] = 0.f; }
  for (int tt = 0; tt < 5; ++tt) {
    __syncthreads();
    for (int u = tid; u < 2048; u += 256) {
      int tg = u >> 10, idx = u & 1023;
      tile[tg][idx] = xw32[((size_t)bc*10 + tg*5 + tt)*1024 + idx];
    }
    __syncthreads();
    float xr = 0.f, xi = 0.f;
    for (int h = 0; h < 128; ++h) {
      unsigned uv = tile[tpar][h*8 + kwi];
      float vx = f16f((u16)uv);
      float vy = f16f((u16)(uv >> 16));
      float2 tw = tw128[(h*kh) & 127];
      xr += vx*tw.x - vy*tw.y;
      xi += vx*tw.y + vy*tw.x;
    }
    int t = tpar*5 + tt;
    float sb, cb; sincosf(TWO_PI * (float)t / 10.0f, &sb, &cb);
    float p_r[10], p_i[10];
    p_r[0] = 1.f; p_i[0] = 0.f; p_r[1] = cb; p_i[1] = -sb;
    #pragma unroll
    for (int k = 2; k < 10; ++k) {
      p_r[k] = p_r[k-1]*p_r[1] - p_i[k-1]*p_i[1];
      p_i[k] = p_r[k-1]*p_i[1] + p_i[k-1]*p_r[1];
    }
    #pragma unroll
    for (int kti = 0; kti < 8; ++kti) {
      int kt = (kti < 4) ? kti : kti + 2;
      accr[kti] += xr*p_r[kt] - xi*p_i[kt];
      acci[kti] += xr*p_i[kt] + xi*p_r[kt];
    }
  }
  __syncthreads();
  if (tpar == 1) {
    #pragma unroll
    for (int kti = 0; kti < 8; ++kti)
      parts1[j*8 + kti] = make_float2(accr[kti], acci[kti]);
  }
  __syncthreads();
  if (tpar == 0) {
    #pragma unroll
    for (int kti = 0; kti < 8; ++kti) {
      float2 bq = parts1[j*8 + kti];
      xf[((size_t)b*1024 + kti*128 + j)*64 + c] =
          make_float2((accr[kti] + bq.x)*ORTHO_SC, (acci[kti] + bq.y)*ORTHO_SC);
    }
  }
}

// ---------------- channel mix (reads spec_w original layout directly) ----------------
__global__ __launch_bounds__(256) void k_mix(const float2* __restrict__ xf,
                                             const float* __restrict__ spec_w_l,
                                             float2* __restrict__ yf) {
  __shared__ float2 xfs[8][4][64];
  int m0 = blockIdx.x * 4;
  for (int i = threadIdx.x; i < 2048; i += 256) {
    int bb = i >> 8, mi = (i >> 6) & 3, ci = i & 63;
    xfs[bb][mi][ci] = xf[((size_t)bb*1024 + m0 + mi)*64 + ci];
  }
  __syncthreads();
  int co = threadIdx.x & 63, mi = threadIdx.x >> 6;
  int m = m0 + mi;
  int kti = m >> 7, khi = (m >> 3) & 15, kwi = m & 7;
  int q = ((kti >= 4) ? 2 : 0) + ((khi >= 8) ? 1 : 0);
  int modeidx = ((kti & 3)*8 + (khi & 7))*8 + kwi;
  const float2* wp = (const float2*)spec_w_l
                     + ((size_t)(q*64)*64 + co)*256 + modeidx;
  float accr[8], acci[8];
  #pragma unroll
  for (int bb = 0; bb < 8; ++bb) { accr[bb] = 0.f; acci[bb] = 0.f; }
  for (int ci = 0; ci < 64; ++ci) {
    float2 wv = wp[(size_t)ci*16384];
    #pragma unroll
    for (int bb = 0; bb < 8; ++bb) {
      float2 xv = xfs[bb][mi][ci];
      accr[bb] += xv.x*wv.x - xv.y*wv.y;
      acci[bb] += xv.x*wv.y + xv.y*wv.x;
    }
  }
  #pragma unroll
  for (int bb = 0; bb < 8; ++bb)
    yf[((size_t)bb*64 + co)*1024 + m] = make_float2(accr[bb], acci[bb]);
}

// ---------------- fused inverse T+H stages (fp16-packed output) ----------------
__global__ __launch_bounds__(256) void k_invTH(const float2* __restrict__ yf,
                                               unsigned* __restrict__ zh16) {
  __shared__ float2 ybuf[1024];
  __shared__ float2 ztb[2][128];
  __shared__ float2 tw128[128];
  int bc = blockIdx.x;
  int b = bc >> 6, c = bc & 63;
  int tid = threadIdx.x;
  for (int u = tid; u < 1024; u += 256) ybuf[u] = yf[(size_t)bc*1024 + u];
  if (tid < 128) {
    float s, co; sincosf(TWO_PI * (float)tid / 128.0f, &s, &co);
    tw128[tid] = make_float2(co, s);
  }
  int tpar = tid >> 7, j = tid & 127;
  __syncthreads();
  for (int tt = 0; tt < 5; ++tt) {
    int t = tt*2 + tpar;
    {
      float sb, cb; sincosf(TWO_PI * (float)t / 10.0f, &sb, &cb);
      float p_r[10], p_i[10];
      p_r[0] = 1.f; p_i[0] = 0.f; p_r[1] = cb; p_i[1] = sb;
      #pragma unroll
      for (int k = 2; k < 10; ++k) {
        p_r[k] = p_r[k-1]*p_r[1] - p_i[k-1]*p_i[1];
        p_i[k] = p_r[k-1]*p_i[1] + p_i[k-1]*p_r[1];
      }
      float zr = 0.f, zi = 0.f;
      #pragma unroll
      for (int kti = 0; kti < 8; ++kti) {
        int kt = (kti < 4) ? kti : kti + 2;
        float2 v = ybuf[kti*128 + j];
        zr += v.x*p_r[kt] - v.y*p_i[kt];
        zi += v.x*p_i[kt] + v.y*p_r[kt];
      }
      ztb[tpar][j] = make_float2(zr*ORTHO_SC, zi*ORTHO_SC);
    }
    __syncthreads();
    {
      int h = j;
      float ar[8], ai[8];
      #pragma unroll
      for (int kw = 0; kw < 8; ++kw) { ar[kw] = 0.f; ai[kw] = 0.f; }
      #pragma unroll
      for (int khi = 0; khi < 16; ++khi) {
        int kh = (khi < 8) ? khi : (112 + khi);
        float2 tw = tw128[(h*kh) & 127];
        #pragma unroll
        for (int kw = 0; kw < 8; ++kw) {
          float2 v = ztb[tpar][khi*8 + kw];
          ar[kw] += v.x*tw.x - v.y*tw.y;
          ai[kw] += v.x*tw.y + v.y*tw.x;
        }
      }
      unsigned* dst = zh16 + (((size_t)(b*10 + t)*128 + h)*64 + c)*8;
      #pragma unroll
      for (int kw = 0; kw < 8; ++kw)
        dst[kw] = (unsigned)f16b(ar[kw]) | ((unsigned)f16b(ai[kw]) << 16);
    }
    __syncthreads();
  }
}

// ---------------- fused inverse-W + skip + GELU (+ next-layer fwdW DFT) ----------------
// T-block uses hi-half twiddles only; Th loaded at use (48 VGPR); (256,5).
__global__ __launch_bounds__(256, 5) void k_invW_mfma(const u16* __restrict__ xTin,
                                                      const unsigned* __restrict__ zh16,
                                                      const u16* __restrict__ swf_l,
                                                      const u16* __restrict__ Tt,
                                                      const u16* __restrict__ Ef,
                                                      const float* __restrict__ skb,
                                                      u16* __restrict__ xTo,
                                                      u16* __restrict__ xw16,
                                                      int do_dft) {
  __shared__ __align__(16) char smem[20480];
  u16* B = (u16*)smem;              // [128][72]
  u16* zAh = (u16*)(smem + 18432);  // [64][16]
  int tid = threadIdx.x;
  int bth = blockIdx.x;
  int lane = tid & 63;
  int wq = tid >> 6;
  int cL = lane & 15;
  int g = lane >> 4;

  {
    const uint4* xsrc = (const uint4*)(xTin + (size_t)bth*8192);
    for (int u = tid; u < 1024; u += 256) {
      int w = u >> 3, c = u & 7;
      ((uint4*)(B + w*72))[c] = xsrc[u];
    }
  }
  {
    const unsigned* zsrc = zh16 + (size_t)bth*512;
    for (int u = tid; u < 512; u += 256) {
      int co = u >> 3, m = u & 7;
      *(unsigned*)(zAh + co*16 + 2*m) = zsrc[u];
    }
  }
  __syncthreads();

  f32x4 acc[4][2];
  #pragma unroll
  for (int s = 0; s < 4; ++s)
    #pragma unroll
    for (int t2 = 0; t2 < 2; ++t2) acc[s][t2] = (f32x4){0.f,0.f,0.f,0.f};

  #pragma unroll
  for (int kb = 0; kb < 2; ++kb) {
    f16x8 Ah[4], Al[4];
    #pragma unroll
    for (int s = 0; s < 4; ++s) {
      Ah[s] = *(const f16x8*)(swf_l + (size_t)(s*2048 + kb*1024 + lane*8));
      Al[s] = *(const f16x8*)(swf_l + (size_t)(s*2048 + kb*1024 + 512 + lane*8));
    }
    #pragma unroll
    for (int t2 = 0; t2 < 2; ++t2) {
      int wrow = wq*32 + t2*16 + cL;
      f16x8 bh = *(const f16x8*)(B + wrow*72 + kb*32 + g*8);
      #pragma unroll
      for (int s = 0; s < 4; ++s) {
        MFMAH(acc[s][t2], Ah[s], bh);
        MFMAH(acc[s][t2], Al[s], bh);
      }
    }
  }
  {
    f16x8 Azh[4];
    f16x8 zero8 = {0,0,0,0,0,0,0,0};
    #pragma unroll
    for (int s = 0; s < 4; ++s)
      Azh[s] = (g < 2) ? *(const f16x8*)(zAh + (s*16 + cL)*16 + g*8) : zero8;
    #pragma unroll
    for (int t2 = 0; t2 < 2; ++t2) {
      int wrow = wq*32 + t2*16 + cL;
      f16x8 th = *(const f16x8*)(Tt + wrow*32 + g*8);
      #pragma unroll
      for (int s = 0; s < 4; ++s) {
        MFMAH(acc[s][t2], Azh[s], th);
      }
    }
  }

  __syncthreads();
  unsigned* out32 = (unsigned*)smem;           // [32][130] u32 (aliases B)
  #pragma unroll
  for (int s = 0; s < 4; ++s) {
    float4 b4 = *(const float4*)(skb + s*16 + g*4);
    float bb[4] = {b4.x, b4.y, b4.z, b4.w};
    #pragma unroll
    for (int t2 = 0; t2 < 2; ++t2) {
      int w = wq*32 + t2*16 + cL;
      u16 gb[4];
      #pragma unroll
      for (int r = 0; r < 4; ++r) {
        float val = acc[s][t2][r] + bb[r];
        gb[r] = f16b(gelu_fast(val));
      }
      out32[(s*8 + g*2 + 0)*130 + w] = (unsigned)gb[0] | ((unsigned)gb[1] << 16);
      out32[(s*8 + g*2 + 1)*130 + w] = (unsigned)gb[2] | ((unsigned)gb[3] << 16);
    }
  }
  __syncthreads();
  {
    uint4* xdst = (uint4*)(xTo + (size_t)bth*8192);
    for (int u = tid; u < 1024; u += 256) {
      int w = u >> 3, c = u & 7;
      unsigned r0 = out32[(c*4 + 0)*130 + w];
      unsigned r1 = out32[(c*4 + 1)*130 + w];
      unsigned r2 = out32[(c*4 + 2)*130 + w];
      unsigned r3 = out32[(c*4 + 3)*130 + w];
      xdst[u] = make_uint4(r0, r1, r2, r3);
    }
  }
  if (do_dft) {
    f32x4 acc2 = (f32x4){0.f,0.f,0.f,0.f};
    int row = wq*8 + (cL >> 1);
    int sh = (cL & 1) * 16;
    #pragma unroll
    for (int kc = 0; kc < 4; ++kc) {
      const unsigned* p = out32 + row*130 + kc*32 + g*8;
      uint2 d0 = *(const uint2*)(p);
      uint2 d1 = *(const uint2*)(p + 2);
      uint2 d2 = *(const uint2*)(p + 4);
      uint2 d3 = *(const uint2*)(p + 6);
      f16x8 a;
      a[0] = __builtin_bit_cast(f16, (u16)(d0.x >> sh));
      a[1] = __builtin_bit_cast(f16, (u16)(d0.y >> sh));
      a[2] = __builtin_bit_cast(f16, (u16)(d1.x >> sh));
      a[3] = __builtin_bit_cast(f16, (u16)(d1.y >> sh));
      a[4] = __builtin_bit_cast(f16, (u16)(d2.x >> sh));
      a[5] = __builtin_bit_cast(f16, (u16)(d2.y >> sh));
      a[6] = __builtin_bit_cast(f16, (u16)(d3.x >> sh));
      a[7] = __builtin_bit_cast(f16, (u16)(d3.y >> sh));
      f16x8 eh = *(const f16x8*)(Ef + (kc*64 + lane)*8);
      f16x8 el = *(const f16x8*)(Ef + 2048 + (kc*64 + lane)*8);
      MFMAH(acc2, a, eh);
      MFMAH(acc2, a, el);
    }
    int h = bth & 127; int bt = bth >> 7; int t = bt % 10, b = bt / 10;
    #pragma unroll
    for (int r = 0; r < 4; ++r) {
      int co = wq*16 + g*4 + r;
      size_t row2 = ((size_t)(b*64 + co)*10 + t)*128 + h;
      xw16[row2*16 + cL] = f16b(acc2[r]);
    }
  }
}

// ---------------- aggregation (K=640) as fp16 MFMA (double-buffered staging) ----------------
__global__ __launch_bounds__(256) void k_agg_mfma(const u16* __restrict__ xT,
                                                  const u16* __restrict__ awf,
                                                  const float* __restrict__ agg_b,
                                                  float* __restrict__ xa) {
  __shared__ __align__(16) u16 B[2][128*72];   // 2 x 18432 B
  int tid = threadIdx.x;
  int bid = blockIdx.x;
  int h = bid & 127, b = bid >> 7;
  int lane = tid & 63;
  int wq = tid >> 6;
  int cL = lane & 15;
  int g = lane >> 4;

  f32x4 acc[4][2];
  #pragma unroll
  for (int s = 0; s < 4; ++s)
    #pragma unroll
    for (int t2 = 0; t2 < 2; ++t2) acc[s][t2] = (f32x4){0.f,0.f,0.f,0.f};

  // prologue: stage t=0 into buf 0
  {
    const uint4* xsrc = (const uint4*)(xT + ((size_t)(b*10 + 0)*128 + h)*8192);
    for (int u = tid; u < 1024; u += 256) {
      int w = u >> 3, c = u & 7;
      ((uint4*)(B[0] + w*72))[c] = xsrc[u];
    }
  }
  __syncthreads();

  for (int t = 0; t < 10; ++t) {
    int cur = t & 1;
    // stage t+1 into the other buffer (overlaps MFMA below)
    if (t + 1 < 10) {
      const uint4* xsrc = (const uint4*)(xT + ((size_t)(b*10 + t + 1)*128 + h)*8192);
      for (int u = tid; u < 1024; u += 256) {
        int w = u >> 3, c = u & 7;
        ((uint4*)(B[cur ^ 1] + w*72))[c] = xsrc[u];
      }
    }
    #pragma unroll
    for (int kc = 0; kc < 2; ++kc) {
      f16x8 Ah[4], Al[4];
      #pragma unroll
      for (int s = 0; s < 4; ++s) {
        const u16* af = awf + (size_t)((s*10 + t)*4 + kc*2)*512;
        Ah[s] = *(const f16x8*)(af + lane*8);
        Al[s] = *(const f16x8*)(af + 512 + lane*8);
      }
      #pragma unroll
      for (int t2 = 0; t2 < 2; ++t2) {
        int wrow = wq*32 + t2*16 + cL;
        f16x8 bh = *(const f16x8*)(B[cur] + wrow*72 + kc*32 + g*8);
        #pragma unroll
        for (int s = 0; s < 4; ++s) {
          MFMAH(acc[s][t2], Ah[s], bh);
          MFMAH(acc[s][t2], Al[s], bh);
        }
      }
    }
    __syncthreads();
  }

  #pragma unroll
  for (int s = 0; s < 4; ++s) {
    float4 b4 = *(const float4*)(agg_b + s*16 + g*4);
    float bb[4] = {b4.x, b4.y, b4.z, b4.w};
    #pragma unroll
    for (int t2 = 0; t2 < 2; ++t2) {
      int w = wq*32 + t2*16 + cL;
      #pragma unroll
      for (int r = 0; r < 4; ++r) {
        int co = s*16 + g*4 + r;
        xa[((size_t)(b*64 + co)*128 + h)*128 + w] = acc[s][t2][r] + bb[r];
      }
    }
  }
}

// ---------------- head as split-fp16 MFMA: M=128 o, N=128 w, K=96 ----------------
__global__ __launch_bounds__(256) void k_head_mfma(const float* __restrict__ xa,
                                                   const u16* __restrict__ f1f,
                                                   const float* __restrict__ fc2_w,
                                                   const float* __restrict__ fc2_b,
                                                   float* __restrict__ out) {
  __shared__ __align__(16) u16 B[128*128];   // 32768 B
  __shared__ float w2s[1280];
  int tid = threadIdx.x;
  int bid = blockIdx.x;
  int h = bid & 127, b = bid >> 7;
  for (int i = tid; i < 1280; i += 256) w2s[i] = fc2_w[i];
  for (int u = tid; u < 2048; u += 256) {
    int co = u >> 5, w4 = u & 31;
    float4 v = *(const float4*)(xa + ((size_t)(b*64 + co)*128 + h)*128 + w4*4);
    float vv[4] = {v.x, v.y, v.z, v.w};
    int kg = co >> 3, kj = co & 7;
    #pragma unroll
    for (int jj = 0; jj < 4; ++jj) {
      int w = w4*4 + jj;
      B[w*128 + ((kg ^ (w & 7)) << 3) + kj] = f16b(vv[jj]);
    }
  }
  for (int u = tid; u < 512; u += 256) {
    int w = u & 127, kgo = u >> 7;
    int kg = 8 + kgo;
    u16* dst = &B[w*128 + ((kg ^ (w & 7)) << 3)];
    if (kgo == 0) {
      float gx = -1.f + 2.f*(float)w/127.f;
      float gy = -1.f + 2.f*(float)h/127.f;
      dst[0] = f16b(gx); dst[1] = f16b(gy); dst[2] = f16b(1.f);
      dst[3] = 0; dst[4] = 0; dst[5] = 0; dst[6] = 0; dst[7] = 0;
    } else {
      #pragma unroll
      for (int q = 0; q < 8; ++q) dst[q] = 0;
    }
  }
  __syncthreads();

  int lane = tid & 63, wq = tid >> 6, cL = lane & 15, g = lane >> 4;
  f32x4 acc[8][2];
  #pragma unroll
  for (int s = 0; s < 8; ++s)
    #pragma unroll
    for (int t2 = 0; t2 < 2; ++t2) acc[s][t2] = (f32x4){0.f,0.f,0.f,0.f};

  #pragma unroll
  for (int kc = 0; kc < 3; ++kc) {
    f16x8 bfr[2];
    #pragma unroll
    for (int t2 = 0; t2 < 2; ++t2) {
      int wrow = wq*32 + t2*16 + cL;
      int kg = kc*4 + g;
      bfr[t2] = *(const f16x8*)(&B[wrow*128 + ((kg ^ (wrow & 7)) << 3)]);
    }
    #pragma unroll
    for (int s = 0; s < 8; ++s) {
      f16x8 Ah = *(const f16x8*)(f1f + (size_t)(((s*3 + kc)*2 + 0)*64 + lane)*8);
      f16x8 Al = *(const f16x8*)(f1f + (size_t)(((s*3 + kc)*2 + 1)*64 + lane)*8);
      #pragma unroll
      for (int t2 = 0; t2 < 2; ++t2) {
        MFMAH(acc[s][t2], Ah, bfr[t2]);
        MFMAH(acc[s][t2], Al, bfr[t2]);
      }
    }
  }

  float o2[2][10];
  #pragma unroll
  for (int t2 = 0; t2 < 2; ++t2)
    #pragma unroll
    for (int j = 0; j < 10; ++j) o2[t2][j] = 0.f;
  #pragma unroll
  for (int s = 0; s < 8; ++s) {
    #pragma unroll
    for (int t2 = 0; t2 < 2; ++t2) {
      #pragma unroll
      for (int r = 0; r < 4; ++r) {
        int o = s*16 + g*4 + r;
        float gl = gelu_fast(acc[s][t2][r]);
        #pragma unroll
        for (int j = 0; j < 10; ++j) o2[t2][j] += gl * w2s[o*10 + j];
      }
    }
  }
  #pragma unroll
  for (int t2 = 0; t2 < 2; ++t2)
    #pragma unroll
    for (int j = 0; j < 10; ++j) {
      float v = o2[t2][j];
      v += __shfl_xor(v, 16, 64);
      v += __shfl_xor(v, 32, 64);
      o2[t2][j] = v;
    }
  if (g == 0) {
    #pragma unroll
    for (int t2 = 0; t2 < 2; ++t2) {
      int w = wq*32 + t2*16 + cL;
      float* dst = out + ((size_t)bid*128 + w)*10;
      float tot[10];
      #pragma unroll
      for (int j = 0; j < 10; ++j) tot[j] = o2[t2][j] + fc2_b[j];
      #pragma unroll
      for (int k = 0; k < 5; ++k) dst[k] = tot[2*k];
      #pragma unroll
      for (int k = 0; k < 5; ++k) {
        float sv = tot[2*k+1];
        float sp = fmaxf(sv, 0.f) + log1pf(expf(-fabsf(sv)));
        dst[5 + k] = sp + 1e-4f;
      }
    }
  }
}

extern "C" void kernel_launch(void* const* d_in, const int* in_sizes, int n_in,
                              void* d_out, int out_size, void* d_ws, size_t ws_size,
                              hipStream_t stream) {
  const float* frames = (const float*)d_in[0];
  const float* times  = (const float*)d_in[1];
  const float* lift_w = (const float*)d_in[2];
  const float* lift_b = (const float*)d_in[3];
  const float* spec_w = (const float*)d_in[4];
  const float* skip_w = (const float*)d_in[5];
  const float* skip_b = (const float*)d_in[6];
  const float* agg_w  = (const float*)d_in[7];
  const float* agg_b  = (const float*)d_in[8];
  const float* fc1_w  = (const float*)d_in[9];
  const float* fc1_b  = (const float*)d_in[10];
  const float* fc2_w  = (const float*)d_in[11];
  const float* fc2_b  = (const float*)d_in[12];
  float* out = (float*)d_out;
  char* ws = (char*)d_ws;

  size_t off = 0;
  u16*      xT  = (u16*)(ws + off);      off += (size_t)10240*8192*2;       // 167,772,160
  u16*      xw16= (u16*)(ws + off);      off += (size_t)655360*16*2;        // 20,971,520
  float2*   xf  = (float2*)(ws + off);   off += (size_t)8*1024*64*8;        // 4,194,304
  float2*   yf  = (float2*)(ws + off);   off += (size_t)8*1024*64*8;        // 4,194,304
  unsigned* zh16= (unsigned*)(ws + off); off += (size_t)10240*512*4;        // 20,971,520
  float*    xa  = (float*)(ws + off);    off += (size_t)8*64*128*128*4;     // 33,554,432
  u16*      swf = (u16*)(ws + off);      off += (size_t)32768*2;            // 65,536
  u16*      awf = (u16*)(ws + off);      off += (size_t)81920*2;            // 163,840
  u16*      Tt  = (u16*)(ws + off);      off += (size_t)8192*2;             // 16,384
  u16*      Ef  = (u16*)(ws + off);      off += (size_t)4096*2;             // 8,192
  u16*      f1f = (u16*)(ws + off);      off += (size_t)24576*2;            // 49,152

  k_prep2<<<584, 256, 0, stream>>>(skip_w, agg_w, fc1_w, fc1_b,
                                   swf, awf, Tt, Ef, f1f);
  k_lift_fwdW<<<10240, 128, 0, stream>>>(frames, times, lift_w, lift_b, Ef, xT, xw16);

  for (int l = 0; l < 4; ++l) {
    k_fwdHT<<<512, 256, 0, stream>>>((const unsigned*)xw16, xf);
    k_mix<<<256, 256, 0, stream>>>(xf, spec_w + (size_t)l*4*64*64*256*2, yf);
    k_invTH<<<512, 256, 0, stream>>>(yf, zh16);
    k_invW_mfma<<<10240, 256, 0, stream>>>(xT, zh16, swf + (size_t)l*8192, Tt, Ef,
                                           skip_b + l*64, xT, xw16, (l < 3) ? 1 : 0);
  }
  k_agg_mfma<<<1024, 256, 0, stream>>>(xT, awf, agg_b, xa);
  k_head_mfma<<<1024, 256, 0, stream>>>(xa, f1f, fc2_w, fc2_b, out);
}